// Round 3
// baseline (862.840 us; speedup 1.0000x reference)
//
#include <hip/hip_runtime.h>
#include <hip/hip_bf16.h>

// ---- static device scratch (immune to ws_size; fully rewritten every call) ----
__device__ float g_img[8*16*64*64];    // render output [b,c,64,64]
__device__ float g_a1 [8*16*128*128];  // convT raw -> act1 (in place)
__device__ float g_a2 [8*8*128*128];   // conv1 raw -> act2 (in place)
__device__ float g_sil[8*64*64];
__device__ float g_stats[96];          // [0:16]s1 [16:32]ss1 [32:48]a1 [48:64]b1
                                       // [64:72]s2 [72:80]ss2 [80:88]a2 [88:96]b2

// ---------------------------------------------------------------------------
// K1: volume render. One wave per ray, lane = depth sample. 32768 rays.
// ---------------------------------------------------------------------------
__global__ __launch_bounds__(256) void k_render(
    const float* __restrict__ R, const float* __restrict__ T, const float* __restrict__ Kin,
    const float* __restrict__ feat, const float* __restrict__ dens)
{
  if (blockIdx.x == 0 && threadIdx.x < 96) g_stats[threadIdx.x] = 0.f;

  int wid  = blockIdx.x * 4 + (threadIdx.x >> 6);
  int lane = threadIdx.x & 63;
  int b   = wid >> 12;
  int rem = wid & 4095;
  int h = rem >> 6, w = rem & 63;

  float fx = Kin[b*9+0] * 0.5f;
  float fy = Kin[b*9+4] * 0.5f;
  float cx = Kin[b*9+2] * 0.5f;
  float cy = Kin[b*9+5] * 0.5f;
  float u = (float)w + 0.5f, v = (float)h + 0.5f;
  float dcx = (u - cx)/fx, dcy = (v - cy)/fy, dcz = 1.0f;
  float Rm[9];
  #pragma unroll
  for (int i=0;i<9;i++) Rm[i] = R[b*9+i];
  float T0 = T[b*3+0], T1 = T[b*3+1], T2 = T[b*3+2];
  float dwx = Rm[0]*dcx + Rm[3]*dcy + Rm[6]*dcz;
  float dwy = Rm[1]*dcx + Rm[4]*dcy + Rm[7]*dcz;
  float dwz = Rm[2]*dcx + Rm[5]*dcy + Rm[8]*dcz;
  float ox = -(Rm[0]*T0 + Rm[3]*T1 + Rm[6]*T2);
  float oy = -(Rm[1]*T0 + Rm[4]*T1 + Rm[7]*T2);
  float oz = -(Rm[2]*T0 + Rm[5]*T1 + Rm[8]*T2);

  float depth = 1.2f + (1.6f/63.0f) * (float)lane;
  const float SC = 2.0f*64.0f/63.0f;   // 2/(voxel*(D-1)), voxel=1/64
  float ix = (ox + dwx*depth)*SC;  ix = (ix + 1.0f)*0.5f*63.0f;
  float iy = (oy + dwy*depth)*SC;  iy = (iy + 1.0f)*0.5f*63.0f;
  float iz = (oz + dwz*depth)*SC;  iz = (iz + 1.0f)*0.5f*63.0f;
  float xf = floorf(ix), yf = floorf(iy), zf = floorf(iz);
  float fxr = ix-xf, fyr = iy-yf, fzr = iz-zf;
  int x0 = (int)xf, y0 = (int)yf, z0 = (int)zf;

  int offs[8]; float cw[8];
  #pragma unroll
  for (int k=0;k<8;k++){
    int dx = k&1, dy=(k>>1)&1, dz=(k>>2)&1;
    int xc=x0+dx, yc=y0+dy, zc=z0+dz;
    bool valid = (xc>=0)&(xc<64)&(yc>=0)&(yc<64)&(zc>=0)&(zc<64);
    float wk = (dx?fxr:1.f-fxr)*(dy?fyr:1.f-fyr)*(dz?fzr:1.f-fzr);
    cw[k] = valid ? wk : 0.0f;
    int xcc = min(max(xc,0),63), ycc=min(max(yc,0),63), zcc=min(max(zc,0),63);
    offs[k] = (zcc*64 + ycc)*64 + xcc;
  }

  const float* dp = dens + (size_t)b*262144;
  float sigma = 0.f;
  #pragma unroll
  for (int k=0;k<8;k++) sigma += cw[k]*dp[offs[k]];

  // exclusive prefix product of (1+eps-sigma) across lanes
  float a = 1.0f + 1e-10f - sigma;
  float prod = a;
  #pragma unroll
  for (int off=1; off<64; off<<=1){
    float t = __shfl_up(prod, off, 64);
    if (lane >= off) prod *= t;
  }
  float excl = __shfl_up(prod, 1, 64);
  if (lane == 0) excl = 1.0f;
  float wgt = sigma * excl;

  // opacity = 1 - prod(1-sigma)
  float q = 1.0f - sigma;
  #pragma unroll
  for (int off=32; off>=1; off>>=1) q *= __shfl_xor(q, off, 64);
  if (lane == 0) g_sil[b*4096 + h*64 + w] = 1.0f - q;

  const float* fb = feat + (size_t)b*16*262144;
  #pragma unroll 1
  for (int c=0;c<16;c++){
    const float* pc = fb + (size_t)c*262144;
    float s = 0.f;
    #pragma unroll
    for (int k=0;k<8;k++) s += cw[k]*pc[offs[k]];
    float contrib = wgt * s;
    #pragma unroll
    for (int off=32; off>=1; off>>=1) contrib += __shfl_xor(contrib, off, 64);
    if (lane == 0) g_img[(b*16+c)*4096 + h*64 + w] = contrib;
  }
}

// ---------------------------------------------------------------------------
// K2: ConvTranspose2d(16->16,k=6,s=2) -> g_a1 raw + BN1 stats.
// y[oh,ow] = bt[o] + sum over kh,kw with (oh+kh-3) even in [0,126]:
//            x[i,(oh+kh-3)/2,(ow+kw-3)/2] * wt[i,o,5-kh,5-kw]
// block: 256 thr = 128 cols x 2 rows; one (b,o,input-row j) per block.
// ---------------------------------------------------------------------------
__global__ __launch_bounds__(256) void k_convt(const float* __restrict__ wt,
                                               const float* __restrict__ bt)
{
  __shared__ float wle[16*36];     // [i][kh][kw] pre-flipped
  __shared__ float tile[16*3*64];  // [i][rr][c], input rows j-1..j+1
  __shared__ float red[256];

  int blk = blockIdx.x;
  int j = blk & 63;
  int o = (blk >> 6) & 15;
  int b = blk >> 10;
  int tid = threadIdx.x;

  for (int idx = tid; idx < 576; idx += 256){
    int i = idx / 36; int r = idx % 36; int kh = r/6, kw = r%6;
    wle[idx] = wt[(i*16+o)*36 + (5-kh)*6 + (5-kw)];
  }
  for (int idx = tid; idx < 3072; idx += 256){
    int c = idx & 63; int rr = (idx>>6) % 3; int i = idx / 192;
    int r = j - 1 + rr;
    tile[idx] = (r>=0 && r<64) ? g_img[(b*16+i)*4096 + r*64 + c] : 0.0f;
  }
  __syncthreads();

  int ow = tid & 127;
  int ty = tid >> 7;
  int oh = 2*j + ty;
  float acc = bt[o];
  int kb_h = 1 - (oh & 1);
  int kb_w = 1 - (ow & 1);
  #pragma unroll
  for (int s=0;s<3;s++){
    int kh = kb_h + 2*s;
    int ph = oh + kh - 3;
    int r = ph >> 1;
    if (r < 0 || r > 63) continue;
    int rr = r - j + 1;
    #pragma unroll
    for (int t=0;t<3;t++){
      int kw = kb_w + 2*t;
      int pw = ow + kw - 3;
      int c = pw >> 1;
      if (c < 0 || c > 63) continue;
      float partial = 0.f;
      #pragma unroll
      for (int i=0;i<16;i++)
        partial += tile[i*192 + rr*64 + c] * wle[i*36 + kh*6 + kw];
      acc += partial;
    }
  }
  g_a1[(b*16+o)*16384 + oh*128 + ow] = acc;

  red[tid] = acc; __syncthreads();
  for (int sft=128; sft>0; sft>>=1){ if (tid<sft) red[tid]+=red[tid+sft]; __syncthreads(); }
  if (tid==0) atomicAdd(&g_stats[o], red[0]);
  __syncthreads();
  red[tid] = acc*acc; __syncthreads();
  for (int sft=128; sft>0; sft>>=1){ if (tid<sft) red[tid]+=red[tid+sft]; __syncthreads(); }
  if (tid==0) atomicAdd(&g_stats[16+o], red[0]);
}

// ---------------------------------------------------------------------------
template<int C, int SOFF, int POFF>
__global__ void k_finalize(const float* __restrict__ g, const float* __restrict__ be)
{
  int c = threadIdx.x;
  if (c < C){
    float m  = g_stats[SOFF+c] * (1.0f/131072.f);
    float v2 = g_stats[SOFF+C+c] * (1.0f/131072.f) - m*m;
    float a = g[c] * rsqrtf(v2 + 1e-5f);
    g_stats[POFF+c]   = a;
    g_stats[POFF+C+c] = be[c] - m*a;
  }
}

// ---------------------------------------------------------------------------
// BN + leaky in place.
// ---------------------------------------------------------------------------
template<int STAGE>
__global__ __launch_bounds__(256) void k_act()
{
  const int n = (STAGE==1) ? 2097152 : 1048576;
  const int C = (STAGE==1) ? 16 : 8;
  const int P = (STAGE==1) ? 32 : 80;
  int idx = blockIdx.x*256 + threadIdx.x;
  if (idx >= n) return;
  float* buf = (STAGE==1) ? g_a1 : g_a2;
  int ch = (idx >> 14) & (C-1);
  float x = buf[idx];
  float y = g_stats[P+ch]*x + g_stats[P+C+ch];
  buf[idx] = (y >= 0.f) ? y : 0.01f*y;
}

// ---------------------------------------------------------------------------
// 5x5 conv (pad=2) via LDS tile (20x132). block: 128 cols x 2 rowhalves;
// 16 out rows per block. STAGE1: g_a1(16ch)->g_a2 raw + BN2 stats.
// STAGE2: g_a2(8ch) -> ReLU -> d_out.
// ---------------------------------------------------------------------------
template<int IC, int OC, int STAGE>
__global__ __launch_bounds__(256) void k_conv5(float* __restrict__ outRelu,
                                               const float* __restrict__ wgt,
                                               const float* __restrict__ bias)
{
  __shared__ float tile[20*132];
  __shared__ float wl[IC*25];
  __shared__ float red[256];

  int blk = blockIdx.x;
  int rt = blk & 7;
  int t  = blk >> 3;
  int o  = t % OC;
  int b  = t / OC;
  int tid = threadIdx.x;
  int tx  = tid & 127;
  int ty2 = tid >> 7;

  for (int idx=tid; idx<IC*25; idx+=256) wl[idx] = wgt[o*IC*25 + idx];

  const float* in = (STAGE==1) ? g_a1 : g_a2;
  float bv = bias[o];
  float acc[8];
  #pragma unroll
  for (int k=0;k<8;k++) acc[k] = bv;

  for (int i=0;i<IC;i++){
    for (int idx=tid; idx<2640; idx+=256){
      int row = idx/132, col = idx - row*132;
      int gr = rt*16 - 2 + row, gc = col - 2;
      float vv = 0.f;
      if (gr>=0 && gr<128 && gc>=0 && gc<128)
        vv = in[(b*IC+i)*16384 + gr*128 + gc];
      tile[idx] = vv;
    }
    __syncthreads();
    int lrb = ty2*8;
    #pragma unroll
    for (int dh=0; dh<5; dh++){
      #pragma unroll
      for (int dw=0; dw<5; dw++){
        float wv = wl[i*25 + dh*5 + dw];
        #pragma unroll
        for (int k=0;k<8;k++)
          acc[k] += tile[(lrb + k + dh)*132 + tx + dw] * wv;
      }
    }
    __syncthreads();
  }

  if (STAGE==1){
    #pragma unroll
    for (int k=0;k<8;k++){
      int grow = rt*16 + ty2*8 + k;
      g_a2[(b*OC+o)*16384 + grow*128 + tx] = acc[k];
    }
    float s=0.f, s2=0.f;
    #pragma unroll
    for (int k=0;k<8;k++){ s += acc[k]; s2 += acc[k]*acc[k]; }
    red[tid] = s; __syncthreads();
    for (int sft=128; sft>0; sft>>=1){ if (tid<sft) red[tid]+=red[tid+sft]; __syncthreads(); }
    if (tid==0) atomicAdd(&g_stats[64+o], red[0]);
    __syncthreads();
    red[tid] = s2; __syncthreads();
    for (int sft=128; sft>0; sft>>=1){ if (tid<sft) red[tid]+=red[tid+sft]; __syncthreads(); }
    if (tid==0) atomicAdd(&g_stats[72+o], red[0]);
  } else {
    #pragma unroll
    for (int k=0;k<8;k++){
      int grow = rt*16 + ty2*8 + k;
      outRelu[(b*OC+o)*16384 + grow*128 + tx] = fmaxf(acc[k], 0.f);
    }
  }
}

// ---------------------------------------------------------------------------
// bilinear 2x upsample (half-pixel centers, edge clamp)
// ---------------------------------------------------------------------------
__global__ __launch_bounds__(256) void k_silup(float* __restrict__ outp)
{
  int idx = blockIdx.x*256 + threadIdx.x;
  if (idx >= 8*16384) return;
  int b = idx >> 14;
  int y = (idx >> 7) & 127;
  int x = idx & 127;
  float sy = y*0.5f - 0.25f, sx = x*0.5f - 0.25f;
  float yfl = floorf(sy), xfl = floorf(sx);
  float fy = sy - yfl, fx = sx - xfl;
  int y0 = min(max((int)yfl,0),63), y1 = min(max((int)yfl+1,0),63);
  int x0 = min(max((int)xfl,0),63), x1 = min(max((int)xfl+1,0),63);
  const float* s = g_sil + b*4096;
  float vv = (1.f-fy)*((1.f-fx)*s[y0*64+x0] + fx*s[y0*64+x1])
           +      fy *((1.f-fx)*s[y1*64+x0] + fx*s[y1*64+x1]);
  outp[idx] = vv;
}

// ---------------------------------------------------------------------------
extern "C" void kernel_launch(void* const* d_in, const int* in_sizes, int n_in,
                              void* d_out, int out_size, void* d_ws, size_t ws_size,
                              hipStream_t stream)
{
  const float* R    = (const float*)d_in[0];
  const float* T    = (const float*)d_in[1];
  const float* K    = (const float*)d_in[2];
  const float* feat = (const float*)d_in[3];
  const float* dens = (const float*)d_in[4];
  const float* wt   = (const float*)d_in[5];
  const float* bt   = (const float*)d_in[6];
  const float* g1   = (const float*)d_in[7];
  const float* be1  = (const float*)d_in[8];
  const float* w1   = (const float*)d_in[9];
  const float* b1   = (const float*)d_in[10];
  const float* g2   = (const float*)d_in[11];
  const float* be2  = (const float*)d_in[12];
  const float* w2   = (const float*)d_in[13];
  const float* b2   = (const float*)d_in[14];

  k_render <<<8192, 256, 0, stream>>>(R, T, K, feat, dens);
  k_convt  <<<8192, 256, 0, stream>>>(wt, bt);
  k_finalize<16,0,32><<<1, 64, 0, stream>>>(g1, be1);
  k_act<1> <<<8192, 256, 0, stream>>>();
  k_conv5<16,8,1><<<512, 256, 0, stream>>>(nullptr, w1, b1);
  k_finalize<8,64,80><<<1, 64, 0, stream>>>(g2, be2);
  k_act<2> <<<4096, 256, 0, stream>>>();
  k_conv5<8,3,2><<<192, 256, 0, stream>>>((float*)d_out, w2, b2);
  k_silup  <<<512, 256, 0, stream>>>((float*)d_out + 393216);
}

// Round 4
// 475.401 us; speedup vs baseline: 1.8150x; 1.8150x over previous
//
#include <hip/hip_runtime.h>
#include <hip/hip_bf16.h>

typedef __hip_bfloat16 bf16;
typedef unsigned int uint;
typedef unsigned short ushort;

// ---- static device scratch (immune to ws_size; fully rewritten every call) ----
__device__ bf16  g_volT[8ULL*64*64*64*16]; // feat channel-last bf16 [b][z][y][x][16]
__device__ float g_img[8*16*64*64];        // render output [b,c,64,64]
__device__ float g_a1 [8*16*128*128];      // convT raw
__device__ float g_a2 [8*8*128*128];       // conv1 raw
__device__ float g_sil[8*64*64];
__device__ float g_part[512];              // BN partial sums (sum,sumsq interleaved)
__device__ float g_stats[96];              // [32:48]a1 [48:64]b1  [80:88]a2 [88:96]b2

__device__ __forceinline__ ushort f2bb(float f){
  bf16 h = __float2bfloat16(f);
  return *reinterpret_cast<ushort*>(&h);
}
__device__ __forceinline__ void acc2(uint u, float w, float& a, float& b){
  union { uint u; float f; } lo, hi;
  lo.u = u << 16; hi.u = u & 0xffff0000u;
  a = fmaf(w, lo.f, a); b = fmaf(w, hi.f, b);
}

// ---------------------------------------------------------------------------
// K0: transpose feat [b][c][z][y][x] f32 -> [b][z][y][x][c] bf16
// block = one (b,z,y) row: 16c x 64x tile via LDS.
// ---------------------------------------------------------------------------
__global__ __launch_bounds__(256) void k_transpose(const float* __restrict__ feat)
{
  __shared__ float lt[64*17];
  int blk = blockIdx.x;                 // b*4096 + z*64 + y
  int y = blk & 63, z = (blk>>6)&63, b = blk>>12;
  const float* src = feat + (size_t)b*16*262144 + z*4096 + y*64;
  #pragma unroll
  for (int it=0; it<4; ++it){
    int idx = it*256 + threadIdx.x;
    int c = idx>>6, x = idx&63;
    lt[x*17+c] = src[(size_t)c*262144 + x];
  }
  __syncthreads();
  uint* dst = (uint*)(g_volT + (size_t)blk*1024);
  #pragma unroll
  for (int it=0; it<2; ++it){
    int idx = it*256 + threadIdx.x;     // pair index; 512 pairs
    int x = idx>>3, c2 = (idx&7)*2;
    uint lo = f2bb(lt[x*17+c2]);
    uint hi = f2bb(lt[x*17+c2+1]);
    dst[idx] = lo | (hi<<16);
  }
}

// ---------------------------------------------------------------------------
// K1: volume render. One wave per ray, lane = depth sample. 32768 rays.
// ---------------------------------------------------------------------------
__global__ __launch_bounds__(256) void k_render(
    const float* __restrict__ R, const float* __restrict__ T, const float* __restrict__ Kin,
    const float* __restrict__ dens)
{
  __shared__ float lr[4*64*17];
  __shared__ float lr2[4*64];

  int wid  = blockIdx.x * 4 + (threadIdx.x >> 6);
  int wv   = threadIdx.x >> 6;
  int lane = threadIdx.x & 63;
  int b   = wid >> 12;
  int rem = wid & 4095;
  int h = rem >> 6, w = rem & 63;

  float fx = Kin[b*9+0] * 0.5f;
  float fy = Kin[b*9+4] * 0.5f;
  float cx = Kin[b*9+2] * 0.5f;
  float cy = Kin[b*9+5] * 0.5f;
  float u = (float)w + 0.5f, v = (float)h + 0.5f;
  float dcx = (u - cx)/fx, dcy = (v - cy)/fy, dcz = 1.0f;
  float Rm[9];
  #pragma unroll
  for (int i=0;i<9;i++) Rm[i] = R[b*9+i];
  float T0 = T[b*3+0], T1 = T[b*3+1], T2 = T[b*3+2];
  float dwx = Rm[0]*dcx + Rm[3]*dcy + Rm[6]*dcz;
  float dwy = Rm[1]*dcx + Rm[4]*dcy + Rm[7]*dcz;
  float dwz = Rm[2]*dcx + Rm[5]*dcy + Rm[8]*dcz;
  float ox = -(Rm[0]*T0 + Rm[3]*T1 + Rm[6]*T2);
  float oy = -(Rm[1]*T0 + Rm[4]*T1 + Rm[7]*T2);
  float oz = -(Rm[2]*T0 + Rm[5]*T1 + Rm[8]*T2);

  float depth = 1.2f + (1.6f/63.0f) * (float)lane;
  const float SC = 2.0f*64.0f/63.0f;
  float ix = (ox + dwx*depth)*SC;  ix = (ix + 1.0f)*0.5f*63.0f;
  float iy = (oy + dwy*depth)*SC;  iy = (iy + 1.0f)*0.5f*63.0f;
  float iz = (oz + dwz*depth)*SC;  iz = (iz + 1.0f)*0.5f*63.0f;
  float xf = floorf(ix), yf = floorf(iy), zf = floorf(iz);
  float fxr = ix-xf, fyr = iy-yf, fzr = iz-zf;
  int x0 = (int)xf, y0 = (int)yf, z0 = (int)zf;

  int offs[8]; float cw[8];
  #pragma unroll
  for (int k=0;k<8;k++){
    int dx = k&1, dy=(k>>1)&1, dz=(k>>2)&1;
    int xc=x0+dx, yc=y0+dy, zc=z0+dz;
    bool valid = (xc>=0)&(xc<64)&(yc>=0)&(yc<64)&(zc>=0)&(zc<64);
    float wk = (dx?fxr:1.f-fxr)*(dy?fyr:1.f-fyr)*(dz?fzr:1.f-fzr);
    cw[k] = valid ? wk : 0.0f;
    int xcc = min(max(xc,0),63), ycc=min(max(yc,0),63), zcc=min(max(zc,0),63);
    offs[k] = (zcc*64 + ycc)*64 + xcc;
  }

  // density gathers + feature vector accumulation (independent loads)
  const float* dp = dens + (size_t)b*262144;
  float sigma = 0.f;
  #pragma unroll
  for (int k=0;k<8;k++) sigma += cw[k]*dp[offs[k]];

  float vch[16];
  #pragma unroll
  for (int c=0;c<16;c++) vch[c] = 0.f;
  #pragma unroll
  for (int k=0;k<8;k++){
    const uint4* p = (const uint4*)(g_volT + ((size_t)b*262144 + offs[k])*16);
    uint4 q0 = p[0];
    uint4 q1 = p[1];
    float wk = cw[k];
    acc2(q0.x, wk, vch[0],  vch[1]);
    acc2(q0.y, wk, vch[2],  vch[3]);
    acc2(q0.z, wk, vch[4],  vch[5]);
    acc2(q0.w, wk, vch[6],  vch[7]);
    acc2(q1.x, wk, vch[8],  vch[9]);
    acc2(q1.y, wk, vch[10], vch[11]);
    acc2(q1.z, wk, vch[12], vch[13]);
    acc2(q1.w, wk, vch[14], vch[15]);
  }

  // exclusive prefix product of (1+eps-sigma) across lanes
  float a = 1.0f + 1e-10f - sigma;
  float prod = a;
  #pragma unroll
  for (int off=1; off<64; off<<=1){
    float t = __shfl_up(prod, off, 64);
    if (lane >= off) prod *= t;
  }
  float excl = __shfl_up(prod, 1, 64);
  if (lane == 0) excl = 1.0f;
  float wgt = sigma * excl;

  // opacity = 1 - prod(1-sigma)
  float q = 1.0f - sigma;
  #pragma unroll
  for (int off=32; off>=1; off>>=1) q *= __shfl_xor(q, off, 64);
  if (lane == 0) g_sil[b*4096 + h*64 + w] = 1.0f - q;

  // weighted features -> two-stage LDS reduction across the wave
  #pragma unroll
  for (int c=0;c<16;c++) lr[wv*1088 + lane*17 + c] = wgt * vch[c];
  __syncthreads();
  {
    int qq = lane >> 4, cc = lane & 15;
    float part = 0.f;
    #pragma unroll
    for (int i=0;i<16;i++) part += lr[wv*1088 + (qq*16+i)*17 + cc];
    lr2[wv*64 + qq*16 + cc] = part;
  }
  __syncthreads();
  if (lane < 16){
    float s = lr2[wv*64+lane] + lr2[wv*64+16+lane] + lr2[wv*64+32+lane] + lr2[wv*64+48+lane];
    g_img[(b*16+lane)*4096 + h*64 + w] = s;
  }
}

// ---------------------------------------------------------------------------
// K2: ConvTranspose2d(16->16,k=6,s=2) -> g_a1 raw (no stats).
// block: 256 thr = 128 cols x 2 rows; one (b,o,input-row j) per block.
// ---------------------------------------------------------------------------
__global__ __launch_bounds__(256) void k_convt(const float* __restrict__ wt,
                                               const float* __restrict__ bt)
{
  __shared__ float wle[16*36];     // [i][kh][kw] pre-flipped
  __shared__ float tile[16*3*64];  // [i][rr][c]

  int blk = blockIdx.x;
  int j = blk & 63;
  int o = (blk >> 6) & 15;
  int b = blk >> 10;
  int tid = threadIdx.x;

  for (int idx = tid; idx < 576; idx += 256){
    int i = idx / 36; int r = idx % 36; int kh = r/6, kw = r%6;
    wle[idx] = wt[(i*16+o)*36 + (5-kh)*6 + (5-kw)];
  }
  for (int idx = tid; idx < 3072; idx += 256){
    int c = idx & 63; int rr = (idx>>6) % 3; int i = idx / 192;
    int r = j - 1 + rr;
    tile[idx] = (r>=0 && r<64) ? g_img[(b*16+i)*4096 + r*64 + c] : 0.0f;
  }
  __syncthreads();

  int ow = tid & 127;
  int ty = tid >> 7;
  int oh = 2*j + ty;
  float acc = bt[o];
  int kb_h = 1 - (oh & 1);
  int kb_w = 1 - (ow & 1);
  #pragma unroll
  for (int s=0;s<3;s++){
    int kh = kb_h + 2*s;
    int ph = oh + kh - 3;
    int r = ph >> 1;
    if (r < 0 || r > 63) continue;
    int rr = r - j + 1;
    #pragma unroll
    for (int t=0;t<3;t++){
      int kw = kb_w + 2*t;
      int pw = ow + kw - 3;
      int c = pw >> 1;
      if (c < 0 || c > 63) continue;
      float partial = 0.f;
      #pragma unroll
      for (int i=0;i<16;i++)
        partial += tile[i*192 + rr*64 + c] * wle[i*36 + kh*6 + kw];
      acc += partial;
    }
  }
  g_a1[(b*16+o)*16384 + oh*128 + ow] = acc;
}

// ---------------------------------------------------------------------------
// BN stats pass: per-block partial sum/sumsq. block (c,s): s in 0..15,
// covers 8192 contiguous elems of channel c. STAGE selects g_a1/g_a2.
// ---------------------------------------------------------------------------
template<int C, int STAGE>
__global__ __launch_bounds__(256) void k_stats()
{
  __shared__ float rs[256], rq[256];
  const float* in = (STAGE==1) ? g_a1 : g_a2;
  int blk = blockIdx.x;            // c*16 + s
  int c = blk >> 4, s = blk & 15;
  int b = s >> 1;
  const float4* p4 = (const float4*)(in + ((size_t)(b*C + c))*16384 + (s&1)*8192);
  int tid = threadIdx.x;
  float sum=0.f, sq=0.f;
  #pragma unroll
  for (int j=0;j<8;j++){
    float4 t = p4[j*256 + tid];
    sum += t.x+t.y+t.z+t.w;
    sq  += t.x*t.x+t.y*t.y+t.z*t.z+t.w*t.w;
  }
  rs[tid]=sum; rq[tid]=sq; __syncthreads();
  for (int sft=128;sft>0;sft>>=1){
    if (tid<sft){ rs[tid]+=rs[tid+sft]; rq[tid]+=rq[tid+sft]; }
    __syncthreads();
  }
  if (tid==0){ g_part[blk*2]=rs[0]; g_part[blk*2+1]=rq[0]; }
}

// ---------------------------------------------------------------------------
template<int C, int POFF>
__global__ void k_finalize(const float* __restrict__ g, const float* __restrict__ be)
{
  int c = threadIdx.x;
  if (c < C){
    float s=0.f, q=0.f;
    for (int i=0;i<16;i++){ s += g_part[(c*16+i)*2]; q += g_part[(c*16+i)*2+1]; }
    float m  = s * (1.0f/131072.f);
    float v2 = q * (1.0f/131072.f) - m*m;
    float a = g[c] * rsqrtf(v2 + 1e-5f);
    g_stats[POFF+c]   = a;
    g_stats[POFF+C+c] = be[c] - m*a;
  }
}

// ---------------------------------------------------------------------------
// 5x5 conv (pad=2), BN+leaky fused into the tile load. RT rows per block.
// STAGE1: g_a1(16ch,params@32) -> g_a2 raw. STAGE2: g_a2(8ch,params@80) -> ReLU out.
// ---------------------------------------------------------------------------
template<int IC, int OC, int RT, int STAGE>
__global__ __launch_bounds__(256) void k_conv5(float* __restrict__ outRelu,
                                               const float* __restrict__ wgt,
                                               const float* __restrict__ bias)
{
  const int TR  = RT + 4;
  const int RPT = RT / 2;
  const int NT  = 128 / RT;
  const int P   = (STAGE==1) ? 32 : 80;
  __shared__ float tile[TR*132];
  __shared__ float wl[IC*25];
  __shared__ float pa_s[IC], pb_s[IC];

  int blk = blockIdx.x;
  int rt = blk % NT;
  int t  = blk / NT;
  int o  = t % OC;
  int b  = t / OC;
  int tid = threadIdx.x;
  int tx  = tid & 127;
  int ty2 = tid >> 7;

  for (int idx=tid; idx<IC*25; idx+=256) wl[idx] = wgt[o*IC*25 + idx];
  if (tid < IC){ pa_s[tid] = g_stats[P+tid]; pb_s[tid] = g_stats[P+IC+tid]; }
  __syncthreads();

  const float* in = (STAGE==1) ? g_a1 : g_a2;
  float bv = bias[o];
  float acc[RPT];
  #pragma unroll
  for (int k=0;k<RPT;k++) acc[k] = bv;

  for (int i=0;i<IC;i++){
    float pa = pa_s[i], pb = pb_s[i];
    for (int idx=tid; idx<TR*132; idx+=256){
      int row = idx/132, col = idx - row*132;
      int gr = rt*RT - 2 + row, gc = col - 2;
      float vv = 0.f;
      if (gr>=0 && gr<128 && gc>=0 && gc<128){
        float x = in[(b*IC+i)*16384 + gr*128 + gc];
        float y = pa*x + pb;
        vv = (y >= 0.f) ? y : 0.01f*y;
      }
      tile[idx] = vv;
    }
    __syncthreads();
    int lrb = ty2*RPT;
    #pragma unroll
    for (int dh=0; dh<5; dh++){
      #pragma unroll
      for (int dw=0; dw<5; dw++){
        float wv = wl[i*25 + dh*5 + dw];
        #pragma unroll
        for (int k=0;k<RPT;k++)
          acc[k] += tile[(lrb + k + dh)*132 + tx + dw] * wv;
      }
    }
    __syncthreads();
  }

  #pragma unroll
  for (int k=0;k<RPT;k++){
    int grow = rt*RT + ty2*RPT + k;
    if (STAGE==1)
      g_a2[(b*OC+o)*16384 + grow*128 + tx] = acc[k];
    else
      outRelu[(b*OC+o)*16384 + grow*128 + tx] = fmaxf(acc[k], 0.f);
  }
}

// ---------------------------------------------------------------------------
__global__ __launch_bounds__(256) void k_silup(float* __restrict__ outp)
{
  int idx = blockIdx.x*256 + threadIdx.x;
  if (idx >= 8*16384) return;
  int b = idx >> 14;
  int y = (idx >> 7) & 127;
  int x = idx & 127;
  float sy = y*0.5f - 0.25f, sx = x*0.5f - 0.25f;
  float yfl = floorf(sy), xfl = floorf(sx);
  float fy = sy - yfl, fx = sx - xfl;
  int y0 = min(max((int)yfl,0),63), y1 = min(max((int)yfl+1,0),63);
  int x0 = min(max((int)xfl,0),63), x1 = min(max((int)xfl+1,0),63);
  const float* s = g_sil + b*4096;
  float vv = (1.f-fy)*((1.f-fx)*s[y0*64+x0] + fx*s[y0*64+x1])
           +      fy *((1.f-fx)*s[y1*64+x0] + fx*s[y1*64+x1]);
  outp[idx] = vv;
}

// ---------------------------------------------------------------------------
extern "C" void kernel_launch(void* const* d_in, const int* in_sizes, int n_in,
                              void* d_out, int out_size, void* d_ws, size_t ws_size,
                              hipStream_t stream)
{
  const float* R    = (const float*)d_in[0];
  const float* T    = (const float*)d_in[1];
  const float* K    = (const float*)d_in[2];
  const float* feat = (const float*)d_in[3];
  const float* dens = (const float*)d_in[4];
  const float* wt   = (const float*)d_in[5];
  const float* bt   = (const float*)d_in[6];
  const float* g1   = (const float*)d_in[7];
  const float* be1  = (const float*)d_in[8];
  const float* w1   = (const float*)d_in[9];
  const float* b1   = (const float*)d_in[10];
  const float* g2   = (const float*)d_in[11];
  const float* be2  = (const float*)d_in[12];
  const float* w2   = (const float*)d_in[13];
  const float* b2   = (const float*)d_in[14];

  k_transpose<<<32768, 256, 0, stream>>>(feat);
  k_render   <<<8192, 256, 0, stream>>>(R, T, K, dens);
  k_convt    <<<8192, 256, 0, stream>>>(wt, bt);
  k_stats<16,1><<<256, 256, 0, stream>>>();
  k_finalize<16,32><<<1, 64, 0, stream>>>(g1, be1);
  k_conv5<16,8,16,1><<<512, 256, 0, stream>>>(nullptr, w1, b1);
  k_stats<8,2><<<128, 256, 0, stream>>>();
  k_finalize<8,80><<<1, 64, 0, stream>>>(g2, be2);
  k_conv5<8,3,8,2><<<384, 256, 0, stream>>>((float*)d_out, w2, b2);
  k_silup   <<<512, 256, 0, stream>>>((float*)d_out + 393216);
}

// Round 5
// 451.632 us; speedup vs baseline: 1.9105x; 1.0526x over previous
//
#include <hip/hip_runtime.h>
#include <hip/hip_bf16.h>

typedef __hip_bfloat16 bf16;
typedef unsigned int uint;
typedef unsigned short ushort;

// ---- static device scratch (immune to ws_size; fully rewritten every call) ----
__device__ bf16  g_volT[8ULL*64*64*64*16]; // feat channel-last bf16 [b][z][y][x][16]
__device__ float g_img[8*16*64*64];        // render output [b,c,64,64]
__device__ float g_a1 [8*16*128*128];      // convT raw
__device__ float g_a2 [8*8*128*128];       // conv1 raw
__device__ float g_sil[8*64*64];
__device__ float g_part[16384+1024];       // BN partials: convt 512blk*32, conv1 512blk*2
__device__ float g_stats[96];              // [32:48]a1 [48:64]b1  [80:88]a2 [88:96]b2

__device__ __forceinline__ ushort f2bb(float f){
  bf16 h = __float2bfloat16(f);
  return *reinterpret_cast<ushort*>(&h);
}
__device__ __forceinline__ void acc2(uint u, float w, float& a, float& b){
  union { uint u; float f; } lo, hi;
  lo.u = u << 16; hi.u = u & 0xffff0000u;
  a = fmaf(w, lo.f, a); b = fmaf(w, hi.f, b);
}

// ---------------------------------------------------------------------------
// K0: transpose feat [b][c][z][y][x] f32 -> [b][z][y][x][c] bf16
// ---------------------------------------------------------------------------
__global__ __launch_bounds__(256) void k_transpose(const float* __restrict__ feat)
{
  __shared__ float lt[64*17];
  int blk = blockIdx.x;                 // b*4096 + z*64 + y
  int y = blk & 63, z = (blk>>6)&63, b = blk>>12;
  const float* src = feat + (size_t)b*16*262144 + z*4096 + y*64;
  #pragma unroll
  for (int it=0; it<4; ++it){
    int idx = it*256 + threadIdx.x;
    int c = idx>>6, x = idx&63;
    lt[x*17+c] = src[(size_t)c*262144 + x];
  }
  __syncthreads();
  uint* dst = (uint*)(g_volT + (size_t)blk*1024);
  #pragma unroll
  for (int it=0; it<2; ++it){
    int idx = it*256 + threadIdx.x;     // pair index; 512 pairs
    int x = idx>>3, c2 = (idx&7)*2;
    uint lo = f2bb(lt[x*17+c2]);
    uint hi = f2bb(lt[x*17+c2+1]);
    dst[idx] = lo | (hi<<16);
  }
}

// ---------------------------------------------------------------------------
// K1: volume render. One wave per ray, lane = depth sample. 32768 rays.
// XCD swizzle: b = blockIdx&7 so each batch's volume pins to one XCD's L2.
// ---------------------------------------------------------------------------
__global__ __launch_bounds__(256) void k_render(
    const float* __restrict__ R, const float* __restrict__ T, const float* __restrict__ Kin,
    const float* __restrict__ dens)
{
  __shared__ float lr[4*64*17];
  __shared__ float lr2[4*64];

  int blk  = blockIdx.x;
  int wv   = threadIdx.x >> 6;
  int lane = threadIdx.x & 63;
  int b  = blk & 7;
  int ri = (blk >> 3)*4 + wv;          // 0..4095
  int h = ri >> 6, w = ri & 63;

  float fx = Kin[b*9+0] * 0.5f;
  float fy = Kin[b*9+4] * 0.5f;
  float cx = Kin[b*9+2] * 0.5f;
  float cy = Kin[b*9+5] * 0.5f;
  float u = (float)w + 0.5f, v = (float)h + 0.5f;
  float dcx = (u - cx)/fx, dcy = (v - cy)/fy, dcz = 1.0f;
  float Rm[9];
  #pragma unroll
  for (int i=0;i<9;i++) Rm[i] = R[b*9+i];
  float T0 = T[b*3+0], T1 = T[b*3+1], T2 = T[b*3+2];
  float dwx = Rm[0]*dcx + Rm[3]*dcy + Rm[6]*dcz;
  float dwy = Rm[1]*dcx + Rm[4]*dcy + Rm[7]*dcz;
  float dwz = Rm[2]*dcx + Rm[5]*dcy + Rm[8]*dcz;
  float ox = -(Rm[0]*T0 + Rm[3]*T1 + Rm[6]*T2);
  float oy = -(Rm[1]*T0 + Rm[4]*T1 + Rm[7]*T2);
  float oz = -(Rm[2]*T0 + Rm[5]*T1 + Rm[8]*T2);

  float depth = 1.2f + (1.6f/63.0f) * (float)lane;
  const float SC = 2.0f*64.0f/63.0f;
  float ix = (ox + dwx*depth)*SC;  ix = (ix + 1.0f)*0.5f*63.0f;
  float iy = (oy + dwy*depth)*SC;  iy = (iy + 1.0f)*0.5f*63.0f;
  float iz = (oz + dwz*depth)*SC;  iz = (iz + 1.0f)*0.5f*63.0f;
  float xf = floorf(ix), yf = floorf(iy), zf = floorf(iz);
  float fxr = ix-xf, fyr = iy-yf, fzr = iz-zf;
  int x0 = (int)xf, y0 = (int)yf, z0 = (int)zf;

  int offs[8]; float cw[8];
  #pragma unroll
  for (int k=0;k<8;k++){
    int dx = k&1, dy=(k>>1)&1, dz=(k>>2)&1;
    int xc=x0+dx, yc=y0+dy, zc=z0+dz;
    bool valid = (xc>=0)&(xc<64)&(yc>=0)&(yc<64)&(zc>=0)&(zc<64);
    float wk = (dx?fxr:1.f-fxr)*(dy?fyr:1.f-fyr)*(dz?fzr:1.f-fzr);
    cw[k] = valid ? wk : 0.0f;
    int xcc = min(max(xc,0),63), ycc=min(max(yc,0),63), zcc=min(max(zc,0),63);
    offs[k] = (zcc*64 + ycc)*64 + xcc;
  }

  const float* dp = dens + (size_t)b*262144;
  float sigma = 0.f;
  #pragma unroll
  for (int k=0;k<8;k++) sigma += cw[k]*dp[offs[k]];

  float vch[16];
  #pragma unroll
  for (int c=0;c<16;c++) vch[c] = 0.f;
  #pragma unroll
  for (int k=0;k<8;k++){
    const uint4* p = (const uint4*)(g_volT + ((size_t)b*262144 + offs[k])*16);
    uint4 q0 = p[0];
    uint4 q1 = p[1];
    float wk = cw[k];
    acc2(q0.x, wk, vch[0],  vch[1]);
    acc2(q0.y, wk, vch[2],  vch[3]);
    acc2(q0.z, wk, vch[4],  vch[5]);
    acc2(q0.w, wk, vch[6],  vch[7]);
    acc2(q1.x, wk, vch[8],  vch[9]);
    acc2(q1.y, wk, vch[10], vch[11]);
    acc2(q1.z, wk, vch[12], vch[13]);
    acc2(q1.w, wk, vch[14], vch[15]);
  }

  // exclusive prefix product of (1+eps-sigma) across lanes
  float a = 1.0f + 1e-10f - sigma;
  float prod = a;
  #pragma unroll
  for (int off=1; off<64; off<<=1){
    float t = __shfl_up(prod, off, 64);
    if (lane >= off) prod *= t;
  }
  float excl = __shfl_up(prod, 1, 64);
  if (lane == 0) excl = 1.0f;
  float wgt = sigma * excl;

  // opacity = 1 - prod(1-sigma)
  float q = 1.0f - sigma;
  #pragma unroll
  for (int off=32; off>=1; off>>=1) q *= __shfl_xor(q, off, 64);
  if (lane == 0) g_sil[b*4096 + h*64 + w] = 1.0f - q;

  // weighted features -> two-stage LDS reduction across the wave
  #pragma unroll
  for (int c=0;c<16;c++) lr[wv*1088 + lane*17 + c] = wgt * vch[c];
  __syncthreads();
  {
    int qq = lane >> 4, cc = lane & 15;
    float part = 0.f;
    #pragma unroll
    for (int i=0;i<16;i++) part += lr[wv*1088 + (qq*16+i)*17 + cc];
    lr2[wv*64 + qq*16 + cc] = part;
  }
  __syncthreads();
  if (lane < 16){
    float s = lr2[wv*64+lane] + lr2[wv*64+16+lane] + lr2[wv*64+32+lane] + lr2[wv*64+48+lane];
    g_img[(b*16+lane)*4096 + h*64 + w] = s;
  }
}

// ---------------------------------------------------------------------------
// K2: ConvTranspose2d(16->16,k=6,s=2): block = (b, input-row j), ALL 16 outch
// in registers. Branch-free via parity algebra (rr=s, c=m+t-1) + padded tile.
// Emits per-block BN1 partials (sum,sumsq per channel).
// ---------------------------------------------------------------------------
__global__ __launch_bounds__(256) void k_convt(const float* __restrict__ wt,
                                               const float* __restrict__ bt)
{
  __shared__ float wle[36*16*16];   // [(kh*6+kw)*16+i][o]
  __shared__ float tile[16*3*66];   // [i][rr][c2], c2 = c+1, zero-padded
  __shared__ float sred[4][32];

  int blk = blockIdx.x;             // b*64 + j
  int j = blk & 63, b = blk >> 6;
  int tid = threadIdx.x;

  for (int idx = tid; idx < 9216; idx += 256){
    int o = idx & 15, i = (idx>>4)&15, tap = idx>>8;
    int kh = tap/6, kw = tap - kh*6;
    wle[idx] = wt[(i*16+o)*36 + (5-kh)*6 + (5-kw)];
  }
  for (int idx = tid; idx < 3168; idx += 256){
    int c2 = idx % 66; int r3 = idx / 66; int rr = r3 % 3; int i = r3 / 3;
    int r = j - 1 + rr, c = c2 - 1;
    tile[i*198 + rr*66 + c2] =
      (r>=0 && r<64 && c>=0 && c<64) ? g_img[(b*16+i)*4096 + r*64 + c] : 0.f;
  }
  __syncthreads();

  int ow = tid & 127, ty = tid >> 7;
  int m = ow >> 1, p = ow & 1;
  int oh = 2*j + ty;

  float acc[16];
  #pragma unroll
  for (int o=0;o<16;o++) acc[o] = bt[o];

  #pragma unroll
  for (int s=0;s<3;s++){
    int kh = (1-ty) + 2*s;
    #pragma unroll
    for (int t=0;t<3;t++){
      int kw = (1-p) + 2*t;
      const float4* wp = (const float4*)&wle[(kh*6+kw)*256];
      int c2 = m + t;
      #pragma unroll
      for (int i=0;i<16;i++){
        float x = tile[i*198 + s*66 + c2];
        float4 w0 = wp[i*4+0], w1 = wp[i*4+1], w2 = wp[i*4+2], w3 = wp[i*4+3];
        acc[0] +=x*w0.x; acc[1] +=x*w0.y; acc[2] +=x*w0.z; acc[3] +=x*w0.w;
        acc[4] +=x*w1.x; acc[5] +=x*w1.y; acc[6] +=x*w1.z; acc[7] +=x*w1.w;
        acc[8] +=x*w2.x; acc[9] +=x*w2.y; acc[10]+=x*w2.z; acc[11]+=x*w2.w;
        acc[12]+=x*w3.x; acc[13]+=x*w3.y; acc[14]+=x*w3.z; acc[15]+=x*w3.w;
      }
    }
  }

  size_t base = (size_t)(b*16)*16384 + oh*128 + ow;
  #pragma unroll
  for (int o=0;o<16;o++) g_a1[base + o*16384] = acc[o];

  // BN1 partials: per-wave shfl reduce, then cross-wave via LDS
  int wv = tid >> 6, lane = tid & 63;
  #pragma unroll
  for (int o=0;o<16;o++){
    float s_ = acc[o], q_ = acc[o]*acc[o];
    #pragma unroll
    for (int msk=32; msk>=1; msk>>=1){
      s_ += __shfl_xor(s_, msk, 64);
      q_ += __shfl_xor(q_, msk, 64);
    }
    if (lane == 0){ sred[wv][o*2] = s_; sred[wv][o*2+1] = q_; }
  }
  __syncthreads();
  if (tid < 32)
    g_part[blk*32 + tid] = sred[0][tid]+sred[1][tid]+sred[2][tid]+sred[3][tid];
}

// ---------------------------------------------------------------------------
__global__ __launch_bounds__(256) void k_finalize16(const float* __restrict__ g,
                                                    const float* __restrict__ be)
{
  __shared__ float rs[256], rq[256];
  int tid = threadIdx.x; int c = tid>>4, seg = tid&15;
  float s=0.f, q=0.f;
  for (int k=0;k<32;k++){
    int blk = seg*32+k;
    s += g_part[blk*32 + c*2];
    q += g_part[blk*32 + c*2 + 1];
  }
  rs[tid]=s; rq[tid]=q; __syncthreads();
  for (int sft=8; sft>0; sft>>=1){
    if (seg<sft){ rs[tid]+=rs[tid+sft]; rq[tid]+=rq[tid+sft]; }
    __syncthreads();
  }
  if (seg==0){
    float m = rs[tid]*(1.0f/131072.f);
    float v = rq[tid]*(1.0f/131072.f) - m*m;
    float a = g[c]*rsqrtf(v+1e-5f);
    g_stats[32+c] = a; g_stats[48+c] = be[c]-m*a;
  }
}

__global__ void k_finalize8(const float* __restrict__ g, const float* __restrict__ be)
{
  __shared__ float rs[64], rq[64];
  int tid = threadIdx.x; int c = tid>>3, seg = tid&7;
  float s=0.f, q=0.f;
  for (int rt=0;rt<8;rt++){
    int blk = (seg*8+c)*8+rt;
    s += g_part[16384 + blk*2];
    q += g_part[16384 + blk*2 + 1];
  }
  rs[tid]=s; rq[tid]=q; __syncthreads();
  for (int sft=4; sft>0; sft>>=1){
    if (seg<sft){ rs[tid]+=rs[tid+sft]; rq[tid]+=rq[tid+sft]; }
    __syncthreads();
  }
  if (seg==0){
    float m = rs[tid]*(1.0f/131072.f);
    float v = rq[tid]*(1.0f/131072.f) - m*m;
    float a = g[c]*rsqrtf(v+1e-5f);
    g_stats[80+c] = a; g_stats[88+c] = be[c]-m*a;
  }
}

// ---------------------------------------------------------------------------
// 5x5 conv (pad=2), BN+leaky fused into tile load, register row-window
// (each x read once: (RPT+4) rows x 5 cols), weights in VGPRs per in-ch.
// STAGE1: g_a1(16ch,params@32) -> g_a2 raw + BN2 partials.
// STAGE2: g_a2(8ch,params@80) -> ReLU -> out.
// ---------------------------------------------------------------------------
template<int IC, int OC, int RT, int STAGE>
__global__ __launch_bounds__(256) void k_conv5(float* __restrict__ outp,
                                               const float* __restrict__ wgt,
                                               const float* __restrict__ bias)
{
  const int TR  = RT + 4;
  const int RPT = RT / 2;
  const int NT  = 128 / RT;
  const int P   = (STAGE==1) ? 32 : 80;
  __shared__ float tile[TR*132];
  __shared__ float wl[IC*25];
  __shared__ float pa_s[IC], pb_s[IC];
  __shared__ float sred[4][2];

  int blk = blockIdx.x;
  int rt = blk % NT;
  int t  = blk / NT;
  int o  = t % OC;
  int b  = t / OC;
  int tid = threadIdx.x;
  int tx  = tid & 127;
  int ty2 = tid >> 7;

  for (int idx=tid; idx<IC*25; idx+=256) wl[idx] = wgt[o*IC*25 + idx];
  if (tid < IC){ pa_s[tid] = g_stats[P+tid]; pb_s[tid] = g_stats[P+IC+tid]; }
  __syncthreads();

  const float* in = (STAGE==1) ? g_a1 : g_a2;
  float bv = bias[o];
  float acc[RPT];
  #pragma unroll
  for (int k=0;k<RPT;k++) acc[k] = bv;

  for (int i=0;i<IC;i++){
    float pa = pa_s[i], pb = pb_s[i];
    for (int idx=tid; idx<TR*132; idx+=256){
      int row = idx/132, col = idx - row*132;
      int gr = rt*RT - 2 + row, gc = col - 2;
      float vv = 0.f;
      if (gr>=0 && gr<128 && gc>=0 && gc<128){
        float x = in[(b*IC+i)*16384 + gr*128 + gc];
        float y = pa*x + pb;
        vv = (y >= 0.f) ? y : 0.01f*y;
      }
      tile[idx] = vv;
    }
    __syncthreads();
    float wr[25];
    #pragma unroll
    for (int t2=0;t2<25;t2++) wr[t2] = wl[i*25 + t2];
    int lrb = ty2*RPT;
    #pragma unroll
    for (int row=0; row<RPT+4; ++row){
      const float* tp = &tile[(lrb+row)*132 + tx];
      float x0=tp[0], x1=tp[1], x2=tp[2], x3=tp[3], x4=tp[4];
      #pragma unroll
      for (int k=0;k<RPT;k++){
        int dh = row - k;
        if (dh >= 0 && dh < 5){
          acc[k] += x0*wr[dh*5+0] + x1*wr[dh*5+1] + x2*wr[dh*5+2]
                  + x3*wr[dh*5+3] + x4*wr[dh*5+4];
        }
      }
    }
    __syncthreads();
  }

  #pragma unroll
  for (int k=0;k<RPT;k++){
    int grow = rt*RT + ty2*RPT + k;
    if (STAGE==1)
      g_a2[(b*OC+o)*16384 + grow*128 + tx] = acc[k];
    else
      outp[(b*OC+o)*16384 + grow*128 + tx] = fmaxf(acc[k], 0.f);
  }

  if (STAGE==1){
    float s_=0.f, q_=0.f;
    #pragma unroll
    for (int k=0;k<RPT;k++){ s_ += acc[k]; q_ += acc[k]*acc[k]; }
    #pragma unroll
    for (int msk=32; msk>=1; msk>>=1){
      s_ += __shfl_xor(s_, msk, 64);
      q_ += __shfl_xor(q_, msk, 64);
    }
    int wv = tid >> 6, lane = tid & 63;
    if (lane == 0){ sred[wv][0] = s_; sred[wv][1] = q_; }
    __syncthreads();
    if (tid < 2)
      g_part[16384 + blk*2 + tid] = sred[0][tid]+sred[1][tid]+sred[2][tid]+sred[3][tid];
  }
}

// ---------------------------------------------------------------------------
__global__ __launch_bounds__(256) void k_silup(float* __restrict__ outp)
{
  int idx = blockIdx.x*256 + threadIdx.x;
  if (idx >= 8*16384) return;
  int b = idx >> 14;
  int y = (idx >> 7) & 127;
  int x = idx & 127;
  float sy = y*0.5f - 0.25f, sx = x*0.5f - 0.25f;
  float yfl = floorf(sy), xfl = floorf(sx);
  float fy = sy - yfl, fx = sx - xfl;
  int y0 = min(max((int)yfl,0),63), y1 = min(max((int)yfl+1,0),63);
  int x0 = min(max((int)xfl,0),63), x1 = min(max((int)xfl+1,0),63);
  const float* s = g_sil + b*4096;
  float vv = (1.f-fy)*((1.f-fx)*s[y0*64+x0] + fx*s[y0*64+x1])
           +      fy *((1.f-fx)*s[y1*64+x0] + fx*s[y1*64+x1]);
  outp[idx] = vv;
}

// ---------------------------------------------------------------------------
extern "C" void kernel_launch(void* const* d_in, const int* in_sizes, int n_in,
                              void* d_out, int out_size, void* d_ws, size_t ws_size,
                              hipStream_t stream)
{
  const float* R    = (const float*)d_in[0];
  const float* T    = (const float*)d_in[1];
  const float* K    = (const float*)d_in[2];
  const float* feat = (const float*)d_in[3];
  const float* dens = (const float*)d_in[4];
  const float* wt   = (const float*)d_in[5];
  const float* bt   = (const float*)d_in[6];
  const float* g1   = (const float*)d_in[7];
  const float* be1  = (const float*)d_in[8];
  const float* w1   = (const float*)d_in[9];
  const float* b1   = (const float*)d_in[10];
  const float* g2   = (const float*)d_in[11];
  const float* be2  = (const float*)d_in[12];
  const float* w2   = (const float*)d_in[13];
  const float* b2   = (const float*)d_in[14];

  k_transpose<<<32768, 256, 0, stream>>>(feat);
  k_render   <<<8192, 256, 0, stream>>>(R, T, K, dens);
  k_convt    <<<512, 256, 0, stream>>>(wt, bt);
  k_finalize16<<<1, 256, 0, stream>>>(g1, be1);
  k_conv5<16,8,16,1><<<512, 256, 0, stream>>>(nullptr, w1, b1);
  k_finalize8<<<1, 64, 0, stream>>>(g2, be2);
  k_conv5<8,3,8,2><<<384, 256, 0, stream>>>((float*)d_out, w2, b2);
  k_silup   <<<512, 256, 0, stream>>>((float*)d_out + 393216);
}

// Round 6
// 338.844 us; speedup vs baseline: 2.5464x; 1.3329x over previous
//
#include <hip/hip_runtime.h>
#include <hip/hip_bf16.h>

typedef __hip_bfloat16 bf16;
typedef unsigned int uint;
typedef unsigned short ushort;

using frag  = __attribute__((ext_vector_type(8))) short;
using f32x4 = __attribute__((ext_vector_type(4))) float;

// ---- static device scratch (immune to ws_size; fully rewritten every call) ----
__device__ bf16  g_volT[8ULL*262144*16]; // feat channel-last bf16 [b][z][y][x][16]
__device__ bf16  g_imgT[8*4096*16];      // render out channel-last [b][64][64][16]
__device__ bf16  g_t1 [8*16384*16];      // convT raw channel-last [b][128][128][16]
__device__ bf16  g_a2r[8*16384*8];       // conv1 raw channel-last [b][128][128][8]
__device__ float g_sil[8*4096];
__device__ float g_part [512*32];        // convT BN1 partials (16 sum + 16 sq)
__device__ float g_part2[256*16];        // conv1 BN2 partials (8 sum + 8 sq)
__device__ float g_stats[96];            // [32:48]a1 [48:64]b1 [80:88]a2 [88:96]b2
__device__ bf16  g_wAt[4*5*64*8];        // packed A-frags: convT (class,step,lane,j)
__device__ bf16  g_wA1[13*64*8];         // conv1
__device__ bf16  g_wA2[7*64*8];          // conv2

__device__ __forceinline__ float bup(ushort u){ union{uint u; float f;} x; x.u = ((uint)u)<<16; return x.f; }
__device__ __forceinline__ ushort bdn(float f){ union{ bf16 h; ushort s;} v; v.h = __float2bfloat16(f); return v.s; }
__device__ __forceinline__ uint aff2(uint u, float a0, float b0, float a1, float b1){
  float x0 = bup((ushort)(u & 0xffff)), x1 = bup((ushort)(u >> 16));
  float y0 = fmaf(a0, x0, b0); y0 = y0 >= 0.f ? y0 : 0.01f*y0;
  float y1 = fmaf(a1, x1, b1); y1 = y1 >= 0.f ? y1 : 0.01f*y1;
  return (uint)bdn(y0) | ((uint)bdn(y1) << 16);
}
__device__ __forceinline__ f32x4 mf(frag a, frag b, f32x4 c){
  return __builtin_amdgcn_mfma_f32_16x16x32_bf16(a, b, c, 0, 0, 0);
}
__device__ __forceinline__ void acc2(uint u, float w, float& a, float& b){
  union { uint u; float f; } lo, hi;
  lo.u = u << 16; hi.u = u & 0xffff0000u;
  a = fmaf(w, lo.f, a); b = fmaf(w, hi.f, b);
}

// ---------------------------------------------------------------------------
// K-1: pack per-lane MFMA A-fragments (weights) for the three convs.
// A[m=lane&15 -> o][k = step*32 + (lane>>4)*8 + j]
// ---------------------------------------------------------------------------
__global__ __launch_bounds__(256) void k_wprep(const float* __restrict__ wt,
                                               const float* __restrict__ w1,
                                               const float* __restrict__ w2)
{
  int tid = threadIdx.x;
  // convT: classes (dr,dc); K = tap(s*3+t)*16 + ic, 5 steps (pad tap 9)
  for (int idx = tid; idx < 4*5*64*8; idx += 256){
    int cls = idx / 2560; int rem = idx % 2560;
    int step = rem / 512; int rem2 = rem % 512;
    int lane = rem2 >> 3, j = rem2 & 7;
    int o = lane & 15;
    int k = step*32 + (lane>>4)*8 + j;
    int tau = k >> 4, ic = k & 15;
    int dr = cls >> 1, dc = cls & 1;
    float val = 0.f;
    if (tau < 9){
      int s = tau/3, t = tau%3;
      val = wt[(ic*16 + o)*36 + (4-2*s+dr)*6 + (4-2*t+dc)];
    }
    g_wAt[idx] = __float2bfloat16(val);
  }
  // conv1: K = tap*16 + ic, 13 steps (pad tap 25)
  for (int idx = tid; idx < 13*64*8; idx += 256){
    int step = idx / 512; int rem2 = idx % 512;
    int lane = rem2 >> 3, j = rem2 & 7;
    int o = lane & 15;
    int k = step*32 + (lane>>4)*8 + j;
    int tau = k >> 4, ic = k & 15;
    float val = (tau < 25 && o < 8) ? w1[o*400 + ic*25 + tau] : 0.f;
    g_wA1[idx] = __float2bfloat16(val);
  }
  // conv2: K = tap*8 + ic, 7 steps (pad taps 25..27)
  for (int idx = tid; idx < 7*64*8; idx += 256){
    int step = idx / 512; int rem2 = idx % 512;
    int lane = rem2 >> 3, j = rem2 & 7;
    int o = lane & 15;
    int k = step*32 + (lane>>4)*8 + j;
    int tau = k >> 3, ic = k & 7;
    float val = (tau < 25 && o < 3) ? w2[o*200 + ic*25 + tau] : 0.f;
    g_wA2[idx] = __float2bfloat16(val);
  }
}

// ---------------------------------------------------------------------------
// K0: transpose feat [b][c][z][y][x] f32 -> [b][z][y][x][c] bf16
// ---------------------------------------------------------------------------
__global__ __launch_bounds__(256) void k_transpose(const float* __restrict__ feat)
{
  __shared__ float lt[64*17];
  int blk = blockIdx.x;
  int y = blk & 63, z = (blk>>6)&63, b = blk>>12;
  const float* src = feat + (size_t)b*16*262144 + z*4096 + y*64;
  #pragma unroll
  for (int it=0; it<4; ++it){
    int idx = it*256 + threadIdx.x;
    int c = idx>>6, x = idx&63;
    lt[x*17+c] = src[(size_t)c*262144 + x];
  }
  __syncthreads();
  uint* dst = (uint*)(g_volT + (size_t)blk*1024);
  #pragma unroll
  for (int it=0; it<2; ++it){
    int idx = it*256 + threadIdx.x;
    int x = idx>>3, c2 = (idx&7)*2;
    uint lo = bdn(lt[x*17+c2]);
    uint hi = bdn(lt[x*17+c2+1]);
    dst[idx] = lo | (hi<<16);
  }
}

// ---------------------------------------------------------------------------
// K1: render, lane = pixel (8x8 tile), wave = 16-depth segment.
// grid 512 = 8b x 64 tiles. Output channel-last bf16 g_imgT + g_sil.
// ---------------------------------------------------------------------------
__global__ __launch_bounds__(256) void k_render(
    const float* __restrict__ R, const float* __restrict__ T, const float* __restrict__ Kin,
    const float* __restrict__ dens)
{
  __shared__ float lds_acc[4][64][17];
  __shared__ float lds_T[4][64];
  __shared__ float lds_P[4][64];

  int blk  = blockIdx.x;
  int tid  = threadIdx.x;
  int wv   = tid >> 6;
  int lane = tid & 63;
  int b  = blk & 7;                     // XCD-pinned batch
  int t  = blk >> 3;
  int py0 = (t >> 3) * 8, px0 = (t & 7) * 8;
  int h = py0 + (lane >> 3), w = px0 + (lane & 7);

  float fx = Kin[b*9+0]*0.5f, fy = Kin[b*9+4]*0.5f;
  float cx = Kin[b*9+2]*0.5f, cy = Kin[b*9+5]*0.5f;
  float u = (float)w + 0.5f, v = (float)h + 0.5f;
  float dcx = (u - cx)/fx, dcy = (v - cy)/fy;
  float Rm[9];
  #pragma unroll
  for (int i=0;i<9;i++) Rm[i] = R[b*9+i];
  float T0 = T[b*3+0], T1 = T[b*3+1], T2 = T[b*3+2];
  float dwx = Rm[0]*dcx + Rm[3]*dcy + Rm[6];
  float dwy = Rm[1]*dcx + Rm[4]*dcy + Rm[7];
  float dwz = Rm[2]*dcx + Rm[5]*dcy + Rm[8];
  float ox = -(Rm[0]*T0 + Rm[3]*T1 + Rm[6]*T2);
  float oy = -(Rm[1]*T0 + Rm[4]*T1 + Rm[7]*T2);
  float oz = -(Rm[2]*T0 + Rm[5]*T1 + Rm[8]*T2);

  const float SC = 2.0f*64.0f/63.0f;
  const float* dp = dens + (size_t)b*262144;
  const bf16* vb = g_volT + (size_t)b*262144*16;

  float vch[16];
  #pragma unroll
  for (int c=0;c<16;c++) vch[c] = 0.f;
  float Trun = 1.0f, Pop = 1.0f;

  for (int i=0;i<16;i++){
    float depth = 1.2f + (1.6f/63.0f) * (float)(wv*16 + i);
    float ix = (ox + dwx*depth)*SC;  ix = (ix + 1.0f)*0.5f*63.0f;
    float iy = (oy + dwy*depth)*SC;  iy = (iy + 1.0f)*0.5f*63.0f;
    float iz = (oz + dwz*depth)*SC;  iz = (iz + 1.0f)*0.5f*63.0f;
    float xf = floorf(ix), yf = floorf(iy), zf = floorf(iz);
    float fxr = ix-xf, fyr = iy-yf, fzr = iz-zf;
    int x0 = (int)xf, y0 = (int)yf, z0 = (int)zf;

    int offs[8]; float cw[8];
    #pragma unroll
    for (int k=0;k<8;k++){
      int dx = k&1, dy=(k>>1)&1, dz=(k>>2)&1;
      int xc=x0+dx, yc=y0+dy, zc=z0+dz;
      bool valid = (xc>=0)&(xc<64)&(yc>=0)&(yc<64)&(zc>=0)&(zc<64);
      float wk = (dx?fxr:1.f-fxr)*(dy?fyr:1.f-fyr)*(dz?fzr:1.f-fzr);
      cw[k] = valid ? wk : 0.0f;
      int xcc = min(max(xc,0),63), ycc=min(max(yc,0),63), zcc=min(max(zc,0),63);
      offs[k] = (zcc*64 + ycc)*64 + xcc;
    }
    float sigma = 0.f;
    #pragma unroll
    for (int k=0;k<8;k++) sigma += cw[k]*dp[offs[k]];

    float wgt = sigma * Trun;
    Trun *= (1.0f + 1e-10f - sigma);
    Pop  *= (1.0f - sigma);

    #pragma unroll
    for (int k=0;k<8;k++){
      const uint4* p = (const uint4*)(vb + (size_t)offs[k]*16);
      uint4 q0 = p[0];
      uint4 q1 = p[1];
      float wk = cw[k]*wgt;
      acc2(q0.x, wk, vch[0],  vch[1]);
      acc2(q0.y, wk, vch[2],  vch[3]);
      acc2(q0.z, wk, vch[4],  vch[5]);
      acc2(q0.w, wk, vch[6],  vch[7]);
      acc2(q1.x, wk, vch[8],  vch[9]);
      acc2(q1.y, wk, vch[10], vch[11]);
      acc2(q1.z, wk, vch[12], vch[13]);
      acc2(q1.w, wk, vch[14], vch[15]);
    }
  }

  #pragma unroll
  for (int c=0;c<16;c++) lds_acc[wv][lane][c] = vch[c];
  lds_T[wv][lane] = Trun;
  lds_P[wv][lane] = Pop;
  __syncthreads();

  // combine: wave wv handles px group [wv*16, wv*16+16), lane&3 = c-quad
  {
    int p  = wv*16 + (lane >> 2);
    int c0 = (lane & 3) * 4;
    float pref = 1.0f;
    float s0=0.f, s1=0.f, s2=0.f, s3=0.f;
    #pragma unroll
    for (int ww=0; ww<4; ++ww){
      s0 += pref * lds_acc[ww][p][c0+0];
      s1 += pref * lds_acc[ww][p][c0+1];
      s2 += pref * lds_acc[ww][p][c0+2];
      s3 += pref * lds_acc[ww][p][c0+3];
      pref *= lds_T[ww][p];
    }
    int hh = py0 + (p >> 3), ww2 = px0 + (p & 7);
    if ((lane & 3) == 0){
      float P = lds_P[0][p]*lds_P[1][p]*lds_P[2][p]*lds_P[3][p];
      g_sil[b*4096 + hh*64 + ww2] = 1.0f - P;
    }
    uint lo = (uint)bdn(s0) | ((uint)bdn(s1) << 16);
    uint hi = (uint)bdn(s2) | ((uint)bdn(s3) << 16);
    uint2 pk; pk.x = lo; pk.y = hi;
    *(uint2*)(g_imgT + ((size_t)(b*4096) + hh*64 + ww2)*16 + c0) = pk;
  }
}

// ---------------------------------------------------------------------------
// K2: ConvTranspose2d via MFMA. grid 512 = 8b x 64 input-rows.
// wave = parity class (dr,dc); C[o16][px16], K = 9taps x 16ic (5 steps).
// ---------------------------------------------------------------------------
__global__ __launch_bounds__(256) void k_convt(const float* __restrict__ bt)
{
  __shared__ __align__(16) short tile[3*66*16];  // [row3][c2][ic] bf16
  __shared__ float ssum[4][16], ssq[4][16];

  int blk = blockIdx.x;
  int r = blk & 63, b = blk >> 6;
  int tid = threadIdx.x;

  for (int idx = tid; idx < 396; idx += 256){
    int row3 = idx / 132; int rem = idx - row3*132;
    int c2 = rem >> 1, half = rem & 1;
    int gr = r - 1 + row3, gc = c2 - 1;
    uint4 val = make_uint4(0,0,0,0);
    if (gr>=0 && gr<64 && gc>=0 && gc<64)
      val = *(const uint4*)(g_imgT + ((size_t)(b*4096) + gr*64 + gc)*16 + half*8);
    *(uint4*)(tile + (row3*66 + c2)*16 + half*8) = val;
  }
  __syncthreads();

  int wv = tid >> 6, lane = tid & 63;
  int dr = wv >> 1, dc = wv & 1;
  int quad = lane >> 4, col = lane & 15;
  int ic0 = (quad & 1) * 8;

  f32x4 acc[4];
  #pragma unroll
  for (int n=0;n<4;n++) acc[n] = (f32x4){0.f,0.f,0.f,0.f};

  #pragma unroll
  for (int s5=0; s5<5; ++s5){
    frag a = *(const frag*)(g_wAt + ((wv*5 + s5)*64 + lane)*8);
    int tau = 2*s5 + (quad >> 1);
    if (tau > 8) tau = 0;                   // zero-weight pad; safe read
    int ss = tau/3, tt = tau%3;
    #pragma unroll
    for (int n=0;n<4;n++){
      int c2 = n*16 + col + tt;
      frag bf = *(const frag*)(tile + (ss*66 + c2)*16 + ic0);
      acc[n] = mf(a, bf, acc[n]);
    }
  }

  // epilogue: o = quad*4+reg (rows), px col = n*16+col
  float4 bo = *(const float4*)(bt + quad*4);
  float bor[4] = {bo.x, bo.y, bo.z, bo.w};
  float sv[4] = {0,0,0,0}, qv[4] = {0,0,0,0};
  int orow = 2*r + dr;
  #pragma unroll
  for (int n=0;n<4;n++){
    int ocol = 2*(n*16 + col) + dc;
    bf16* dst = g_t1 + ((size_t)(b*128 + orow)*128 + ocol)*16 + quad*4;
    #pragma unroll
    for (int reg=0;reg<4;reg++){
      float vvv = acc[n][reg] + bor[reg];
      dst[reg] = __float2bfloat16(vvv);
      sv[reg] += vvv; qv[reg] += vvv*vvv;
    }
  }
  #pragma unroll
  for (int m=1; m<16; m<<=1){
    #pragma unroll
    for (int reg=0;reg<4;reg++){
      sv[reg] += __shfl_xor(sv[reg], m, 64);
      qv[reg] += __shfl_xor(qv[reg], m, 64);
    }
  }
  if ((lane & 15) == 0){
    #pragma unroll
    for (int reg=0;reg<4;reg++){
      ssum[wv][quad*4+reg] = sv[reg];
      ssq [wv][quad*4+reg] = qv[reg];
    }
  }
  __syncthreads();
  if (tid < 16){
    g_part[blk*32 + tid]      = ssum[0][tid]+ssum[1][tid]+ssum[2][tid]+ssum[3][tid];
    g_part[blk*32 + 16 + tid] = ssq[0][tid]+ssq[1][tid]+ssq[2][tid]+ssq[3][tid];
  }
}

// ---------------------------------------------------------------------------
__global__ __launch_bounds__(256) void k_fin1(const float* __restrict__ g,
                                              const float* __restrict__ be)
{
  __shared__ float rs[256], rq[256];
  int tid = threadIdx.x; int c = tid>>4, seg = tid&15;
  float s=0.f, q=0.f;
  for (int k=0;k<32;k++){
    int blk = seg*32+k;
    s += g_part[blk*32 + c];
    q += g_part[blk*32 + 16 + c];
  }
  rs[tid]=s; rq[tid]=q; __syncthreads();
  for (int sft=8; sft>0; sft>>=1){
    if (seg<sft){ rs[tid]+=rs[tid+sft]; rq[tid]+=rq[tid+sft]; }
    __syncthreads();
  }
  if (seg==0){
    float m = rs[tid]*(1.0f/131072.f);
    float v = rq[tid]*(1.0f/131072.f) - m*m;
    float a = g[c]*rsqrtf(v+1e-5f);
    g_stats[32+c] = a; g_stats[48+c] = be[c]-m*a;
  }
}

__global__ __launch_bounds__(256) void k_fin2(const float* __restrict__ g,
                                              const float* __restrict__ be)
{
  __shared__ float rs[256], rq[256];
  int tid = threadIdx.x; int seg = tid & 31, c = tid >> 5;
  float s=0.f, q=0.f;
  for (int k=0;k<8;k++){
    int blk = seg*8+k;
    s += g_part2[blk*16 + c];
    q += g_part2[blk*16 + 8 + c];
  }
  rs[tid]=s; rq[tid]=q; __syncthreads();
  for (int sft=16; sft>0; sft>>=1){
    if (seg<sft){ rs[tid]+=rs[tid+sft]; rq[tid]+=rq[tid+sft]; }
    __syncthreads();
  }
  if (seg==0){
    float m = rs[tid]*(1.0f/131072.f);
    float v = rq[tid]*(1.0f/131072.f) - m*m;
    float a = g[c]*rsqrtf(v+1e-5f);
    g_stats[80+c] = a; g_stats[88+c] = be[c]-m*a;
  }
}

// ---------------------------------------------------------------------------
// K3: conv1 5x5 (16->8) via MFMA, BN1+leaky fused into staging.
// grid 256 = 8b x 32 row-tiles (4 rows). wave = row. C[o16][px16], 13 k-steps.
// ---------------------------------------------------------------------------
__global__ __launch_bounds__(256) void k_conv1(const float* __restrict__ b1)
{
  __shared__ __align__(16) short tile[8*132*16];   // 33792 B
  __shared__ float ssum[4][8], ssq[4][8];

  int blk = blockIdx.x;
  int rt = blk & 31, b = blk >> 5;
  int tid = threadIdx.x;

  float pa[16], pb[16];
  #pragma unroll
  for (int c=0;c<16;c++){ pa[c] = g_stats[32+c]; pb[c] = g_stats[48+c]; }

  for (int it=0; it<5; ++it){
    int idx = it*256 + tid;
    if (idx < 1056){
      int r8 = idx / 132; int c2 = idx - r8*132;
      int gr = rt*4 - 2 + r8, gc = c2 - 2;
      uint4 v0 = make_uint4(0,0,0,0), v1 = make_uint4(0,0,0,0);
      if (gr>=0 && gr<128 && gc>=0 && gc<128){
        const bf16* src = g_t1 + ((size_t)(b*128 + gr)*128 + gc)*16;
        v0 = *(const uint4*)(src);
        v1 = *(const uint4*)(src + 8);
        v0.x = aff2(v0.x, pa[0],pb[0],pa[1],pb[1]);
        v0.y = aff2(v0.y, pa[2],pb[2],pa[3],pb[3]);
        v0.z = aff2(v0.z, pa[4],pb[4],pa[5],pb[5]);
        v0.w = aff2(v0.w, pa[6],pb[6],pa[7],pb[7]);
        v1.x = aff2(v1.x, pa[8],pb[8],pa[9],pb[9]);
        v1.y = aff2(v1.y, pa[10],pb[10],pa[11],pb[11]);
        v1.z = aff2(v1.z, pa[12],pb[12],pa[13],pb[13]);
        v1.w = aff2(v1.w, pa[14],pb[14],pa[15],pb[15]);
      }
      *(uint4*)(tile + (r8*132 + c2)*16)     = v0;
      *(uint4*)(tile + (r8*132 + c2)*16 + 8) = v1;
    }
  }
  __syncthreads();

  int wv = tid >> 6, lane = tid & 63;
  int quad = lane >> 4, col = lane & 15;
  int ic0 = (quad & 1) * 8;

  f32x4 acc[8];
  #pragma unroll
  for (int n=0;n<8;n++) acc[n] = (f32x4){0.f,0.f,0.f,0.f};

  for (int s13=0; s13<13; ++s13){
    frag a = *(const frag*)(g_wA1 + (s13*64 + lane)*8);
    int tau = 2*s13 + (quad >> 1);
    if (tau > 24) tau = 0;
    int dh = tau/5, dw = tau%5;
    int rowt = wv + dh;
    #pragma unroll
    for (int n=0;n<8;n++){
      int c2 = n*16 + col + dw;
      frag bf = *(const frag*)(tile + (rowt*132 + c2)*16 + ic0);
      acc[n] = mf(a, bf, acc[n]);
    }
  }

  int row = rt*4 + wv;
  float sv[4] = {0,0,0,0}, qv[4] = {0,0,0,0};
  if (quad < 2){
    float4 bo = *(const float4*)(b1 + quad*4);
    float bor[4] = {bo.x, bo.y, bo.z, bo.w};
    #pragma unroll
    for (int n=0;n<8;n++){
      int px = n*16 + col;
      bf16* dst = g_a2r + ((size_t)(b*128 + row)*128 + px)*8 + quad*4;
      #pragma unroll
      for (int reg=0;reg<4;reg++){
        float vvv = acc[n][reg] + bor[reg];
        dst[reg] = __float2bfloat16(vvv);
        sv[reg] += vvv; qv[reg] += vvv*vvv;
      }
    }
  }
  #pragma unroll
  for (int m=1; m<16; m<<=1){
    #pragma unroll
    for (int reg=0;reg<4;reg++){
      sv[reg] += __shfl_xor(sv[reg], m, 64);
      qv[reg] += __shfl_xor(qv[reg], m, 64);
    }
  }
  if ((lane & 15) == 0 && quad < 2){
    #pragma unroll
    for (int reg=0;reg<4;reg++){
      ssum[wv][quad*4+reg] = sv[reg];
      ssq [wv][quad*4+reg] = qv[reg];
    }
  }
  __syncthreads();
  if (tid < 8){
    g_part2[blk*16 + tid]     = ssum[0][tid]+ssum[1][tid]+ssum[2][tid]+ssum[3][tid];
    g_part2[blk*16 + 8 + tid] = ssq[0][tid]+ssq[1][tid]+ssq[2][tid]+ssq[3][tid];
  }
}

// ---------------------------------------------------------------------------
// K4: conv2 5x5 (8->3) via MFMA, BN2+leaky fused into staging. ReLU -> d_out.
// grid 256 = 8b x 32 row-tiles. 7 k-steps (K = 25taps x 8ic, padded).
// ---------------------------------------------------------------------------
__global__ __launch_bounds__(256) void k_conv2(float* __restrict__ outp,
                                               const float* __restrict__ b2)
{
  __shared__ __align__(16) short tile[8*132*8];   // 16896 B

  int blk = blockIdx.x;
  int rt = blk & 31, b = blk >> 5;
  int tid = threadIdx.x;

  float pa[8], pb[8];
  #pragma unroll
  for (int c=0;c<8;c++){ pa[c] = g_stats[80+c]; pb[c] = g_stats[88+c]; }

  for (int it=0; it<5; ++it){
    int idx = it*256 + tid;
    if (idx < 1056){
      int r8 = idx / 132; int c2 = idx - r8*132;
      int gr = rt*4 - 2 + r8, gc = c2 - 2;
      uint4 v0 = make_uint4(0,0,0,0);
      if (gr>=0 && gr<128 && gc>=0 && gc<128){
        v0 = *(const uint4*)(g_a2r + ((size_t)(b*128 + gr)*128 + gc)*8);
        v0.x = aff2(v0.x, pa[0],pb[0],pa[1],pb[1]);
        v0.y = aff2(v0.y, pa[2],pb[2],pa[3],pb[3]);
        v0.z = aff2(v0.z, pa[4],pb[4],pa[5],pb[5]);
        v0.w = aff2(v0.w, pa[6],pb[6],pa[7],pb[7]);
      }
      *(uint4*)(tile + (r8*132 + c2)*8) = v0;
    }
  }
  __syncthreads();

  int wv = tid >> 6, lane = tid & 63;
  int quad = lane >> 4, col = lane & 15;

  f32x4 acc[8];
  #pragma unroll
  for (int n=0;n<8;n++) acc[n] = (f32x4){0.f,0.f,0.f,0.f};

  for (int s7=0; s7<7; ++s7){
    frag a = *(const frag*)(g_wA2 + (s7*64 + lane)*8);
    int tau = 4*s7 + quad;
    if (tau > 24) tau = 0;
    int dh = tau/5, dw = tau%5;
    int rowt = wv + dh;
    #pragma unroll
    for (int n=0;n<8;n++){
      int c2 = n*16 + col + dw;
      frag bf = *(const frag*)(tile + (rowt*132 + c2)*8);
      acc[n] = mf(a, bf, acc[n]);
    }
  }

  if (quad == 0){
    int row = rt*4 + wv;
    float b2v[3] = {b2[0], b2[1], b2[2]};
    #pragma unroll
    for (int n=0;n<8;n++){
      int px = n*16 + col;
      #pragma unroll
      for (int reg=0;reg<3;reg++){
        float vvv = fmaxf(acc[n][reg] + b2v[reg], 0.f);
        outp[(size_t)(b*3 + reg)*16384 + row*128 + px] = vvv;
      }
    }
  }
}

// ---------------------------------------------------------------------------
__global__ __launch_bounds__(256) void k_silup(float* __restrict__ outp)
{
  int idx = blockIdx.x*256 + threadIdx.x;
  if (idx >= 8*16384) return;
  int b = idx >> 14;
  int y = (idx >> 7) & 127;
  int x = idx & 127;
  float sy = y*0.5f - 0.25f, sx = x*0.5f - 0.25f;
  float yfl = floorf(sy), xfl = floorf(sx);
  float fy = sy - yfl, fx = sx - xfl;
  int y0 = min(max((int)yfl,0),63), y1 = min(max((int)yfl+1,0),63);
  int x0 = min(max((int)xfl,0),63), x1 = min(max((int)xfl+1,0),63);
  const float* s = g_sil + b*4096;
  float vv = (1.f-fy)*((1.f-fx)*s[y0*64+x0] + fx*s[y0*64+x1])
           +      fy *((1.f-fx)*s[y1*64+x0] + fx*s[y1*64+x1]);
  outp[idx] = vv;
}

// ---------------------------------------------------------------------------
extern "C" void kernel_launch(void* const* d_in, const int* in_sizes, int n_in,
                              void* d_out, int out_size, void* d_ws, size_t ws_size,
                              hipStream_t stream)
{
  const float* R    = (const float*)d_in[0];
  const float* T    = (const float*)d_in[1];
  const float* K    = (const float*)d_in[2];
  const float* feat = (const float*)d_in[3];
  const float* dens = (const float*)d_in[4];
  const float* wt   = (const float*)d_in[5];
  const float* bt   = (const float*)d_in[6];
  const float* g1   = (const float*)d_in[7];
  const float* be1  = (const float*)d_in[8];
  const float* w1   = (const float*)d_in[9];
  const float* b1   = (const float*)d_in[10];
  const float* g2   = (const float*)d_in[11];
  const float* be2  = (const float*)d_in[12];
  const float* w2   = (const float*)d_in[13];
  const float* b2   = (const float*)d_in[14];

  k_wprep    <<<1, 256, 0, stream>>>(wt, w1, w2);
  k_transpose<<<32768, 256, 0, stream>>>(feat);
  k_render   <<<512, 256, 0, stream>>>(R, T, K, dens);
  k_convt    <<<512, 256, 0, stream>>>(bt);
  k_fin1     <<<1, 256, 0, stream>>>(g1, be1);
  k_conv1    <<<256, 256, 0, stream>>>(b1);
  k_fin2     <<<1, 256, 0, stream>>>(g2, be2);
  k_conv2    <<<256, 256, 0, stream>>>((float*)d_out, b2);
  k_silup    <<<512, 256, 0, stream>>>((float*)d_out + 393216);
}

// Round 7
// 334.557 us; speedup vs baseline: 2.5790x; 1.0128x over previous
//
#include <hip/hip_runtime.h>
#include <hip/hip_bf16.h>

typedef __hip_bfloat16 bf16;
typedef unsigned int uint;
typedef unsigned short ushort;

using frag  = __attribute__((ext_vector_type(8))) short;
using f32x4 = __attribute__((ext_vector_type(4))) float;

// ---- static device scratch (immune to ws_size; fully rewritten every call) ----
__device__ bf16  g_volT[8ULL*262144*16]; // feat channel-last bf16 [b][z][y][x][16]
__device__ bf16  g_imgT[8*4096*16];      // render out channel-last [b][64][64][16]
__device__ bf16  g_t1 [8*16384*16];      // convT raw channel-last [b][128][128][16]
__device__ bf16  g_a2r[8*16384*8];       // conv1 raw channel-last [b][128][128][8]
__device__ float g_sil[8*4096];
__device__ float g_part [512*32];        // convT BN1 partials (16 sum + 16 sq)
__device__ float g_part2[256*16];        // conv1 BN2 partials (8 sum + 8 sq)
__device__ float g_stats[96];            // [32:48]a1 [48:64]b1 [80:88]a2 [88:96]b2
__device__ bf16  g_wAt[4*5*64*8];        // packed A-frags: convT (class,step,lane,j)
__device__ bf16  g_wA1[13*64*8];         // conv1
__device__ bf16  g_wA2[7*64*8];          // conv2

__device__ __forceinline__ float bup(ushort u){ union{uint u; float f;} x; x.u = ((uint)u)<<16; return x.f; }
__device__ __forceinline__ ushort bdn(float f){ union{ bf16 h; ushort s;} v; v.h = __float2bfloat16(f); return v.s; }
__device__ __forceinline__ uint aff2(uint u, float a0, float b0, float a1, float b1){
  float x0 = bup((ushort)(u & 0xffff)), x1 = bup((ushort)(u >> 16));
  float y0 = fmaf(a0, x0, b0); y0 = y0 >= 0.f ? y0 : 0.01f*y0;
  float y1 = fmaf(a1, x1, b1); y1 = y1 >= 0.f ? y1 : 0.01f*y1;
  return (uint)bdn(y0) | ((uint)bdn(y1) << 16);
}
__device__ __forceinline__ f32x4 mf(frag a, frag b, f32x4 c){
  return __builtin_amdgcn_mfma_f32_16x16x32_bf16(a, b, c, 0, 0, 0);
}
__device__ __forceinline__ void acc2(uint u, float w, float& a, float& b){
  union { uint u; float f; } lo, hi;
  lo.u = u << 16; hi.u = u & 0xffff0000u;
  a = fmaf(w, lo.f, a); b = fmaf(w, hi.f, b);
}

// ---------------------------------------------------------------------------
// K-1: pack per-lane MFMA A-fragments (weights) for the three convs.
// ---------------------------------------------------------------------------
__global__ __launch_bounds__(256) void k_wprep(const float* __restrict__ wt,
                                               const float* __restrict__ w1,
                                               const float* __restrict__ w2)
{
  int tid = threadIdx.x;
  for (int idx = tid; idx < 4*5*64*8; idx += 256){
    int cls = idx / 2560; int rem = idx % 2560;
    int step = rem / 512; int rem2 = rem % 512;
    int lane = rem2 >> 3, j = rem2 & 7;
    int o = lane & 15;
    int k = step*32 + (lane>>4)*8 + j;
    int tau = k >> 4, ic = k & 15;
    int dr = cls >> 1, dc = cls & 1;
    float val = 0.f;
    if (tau < 9){
      int s = tau/3, t = tau%3;
      val = wt[(ic*16 + o)*36 + (4-2*s+dr)*6 + (4-2*t+dc)];
    }
    g_wAt[idx] = __float2bfloat16(val);
  }
  for (int idx = tid; idx < 13*64*8; idx += 256){
    int step = idx / 512; int rem2 = idx % 512;
    int lane = rem2 >> 3, j = rem2 & 7;
    int o = lane & 15;
    int k = step*32 + (lane>>4)*8 + j;
    int tau = k >> 4, ic = k & 15;
    float val = (tau < 25 && o < 8) ? w1[o*400 + ic*25 + tau] : 0.f;
    g_wA1[idx] = __float2bfloat16(val);
  }
  for (int idx = tid; idx < 7*64*8; idx += 256){
    int step = idx / 512; int rem2 = idx % 512;
    int lane = rem2 >> 3, j = rem2 & 7;
    int o = lane & 15;
    int k = step*32 + (lane>>4)*8 + j;
    int tau = k >> 3, ic = k & 7;
    float val = (tau < 25 && o < 3) ? w2[o*200 + ic*25 + tau] : 0.f;
    g_wA2[idx] = __float2bfloat16(val);
  }
}

// ---------------------------------------------------------------------------
// K0: transpose feat [b][c][z][y][x] f32 -> [b][z][y][x][c] bf16.
// grid 8192 = (b, z, y4). float4 reads, LDS stride-17 staging, uint4 writes.
// ---------------------------------------------------------------------------
__global__ __launch_bounds__(256) void k_transpose(const float* __restrict__ feat)
{
  __shared__ float lt[4*64*17];
  int blk = blockIdx.x;                 // b*1024 + z*16 + yq
  int yq = blk & 15, z = (blk>>4)&63, b = blk>>10;
  int y0 = yq*4;
  int tid = threadIdx.x;
  int xq = tid & 15;
  #pragma unroll
  for (int it=0; it<4; ++it){
    int cy = it*16 + (tid>>4);
    int c = cy >> 2, y = cy & 3;
    const float4 vv = *(const float4*)(feat + (size_t)b*4194304 + (size_t)c*262144
                                       + z*4096 + (y0+y)*64 + xq*4);
    float* dst = &lt[(y*64 + xq*4)*17 + c];
    dst[0]=vv.x; dst[17]=vv.y; dst[34]=vv.z; dst[51]=vv.w;
  }
  __syncthreads();
  int y = tid >> 6, x = tid & 63;
  const float* row = &lt[(y*64+x)*17];
  uint pk[8];
  #pragma unroll
  for (int c2=0;c2<8;c2++)
    pk[c2] = (uint)bdn(row[2*c2]) | ((uint)bdn(row[2*c2+1])<<16);
  uint* dst = (uint*)(g_volT + ((size_t)b*262144 + z*4096 + (y0+y)*64 + x)*16);
  uint4 lo; lo.x=pk[0]; lo.y=pk[1]; lo.z=pk[2]; lo.w=pk[3];
  uint4 hi; hi.x=pk[4]; hi.y=pk[5]; hi.z=pk[6]; hi.w=pk[7];
  *(uint4*)dst = lo;
  *(uint4*)(dst+4) = hi;
}

// ---------------------------------------------------------------------------
// K1: render v3. One wave per 8x8 pixel tile, sequential 64-depth march with
// transmittance early-exit + per-lane gather predication. grid 512 x 64thr.
// ---------------------------------------------------------------------------
__global__ __launch_bounds__(64) void k_render(
    const float* __restrict__ R, const float* __restrict__ T, const float* __restrict__ Kin,
    const float* __restrict__ dens)
{
  int blk  = blockIdx.x;
  int lane = threadIdx.x;
  int b  = blk & 7;                     // XCD-pinned batch
  int t  = blk >> 3;
  int py0 = (t >> 3) * 8, px0 = (t & 7) * 8;
  int h = py0 + (lane >> 3), w = px0 + (lane & 7);

  float fx = Kin[b*9+0]*0.5f, fy = Kin[b*9+4]*0.5f;
  float cx = Kin[b*9+2]*0.5f, cy = Kin[b*9+5]*0.5f;
  float u = (float)w + 0.5f, v = (float)h + 0.5f;
  float dcx = (u - cx)/fx, dcy = (v - cy)/fy;
  float Rm[9];
  #pragma unroll
  for (int i=0;i<9;i++) Rm[i] = R[b*9+i];
  float T0 = T[b*3+0], T1 = T[b*3+1], T2 = T[b*3+2];
  float dwx = Rm[0]*dcx + Rm[3]*dcy + Rm[6];
  float dwy = Rm[1]*dcx + Rm[4]*dcy + Rm[7];
  float dwz = Rm[2]*dcx + Rm[5]*dcy + Rm[8];
  float ox = -(Rm[0]*T0 + Rm[3]*T1 + Rm[6]*T2);
  float oy = -(Rm[1]*T0 + Rm[4]*T1 + Rm[7]*T2);
  float oz = -(Rm[2]*T0 + Rm[5]*T1 + Rm[8]*T2);

  const float SC = 2.0f*64.0f/63.0f;
  const float* dp = dens + (size_t)b*262144;
  const bf16* vb = g_volT + (size_t)b*262144*16;

  float vch[16];
  #pragma unroll
  for (int c=0;c<16;c++) vch[c] = 0.f;
  float Trun = 1.0f, Pop = 1.0f;

  for (int d=0; d<64; ++d){
    float depth = 1.2f + (1.6f/63.0f) * (float)d;
    float ix = (ox + dwx*depth)*SC;  ix = (ix + 1.0f)*0.5f*63.0f;
    float iy = (oy + dwy*depth)*SC;  iy = (iy + 1.0f)*0.5f*63.0f;
    float iz = (oz + dwz*depth)*SC;  iz = (iz + 1.0f)*0.5f*63.0f;
    float xf = floorf(ix), yf = floorf(iy), zf = floorf(iz);
    int x0 = (int)xf, y0 = (int)yf, z0 = (int)zf;
    float sigma = 0.f;

    bool anyv = (x0>=-1)&(x0<64)&(y0>=-1)&(y0<64)&(z0>=-1)&(z0<64);
    if (anyv){
      float fxr = ix-xf, fyr = iy-yf, fzr = iz-zf;
      int offs[8]; float cw[8];
      #pragma unroll
      for (int k=0;k<8;k++){
        int dx = k&1, dy=(k>>1)&1, dz=(k>>2)&1;
        int xc=x0+dx, yc=y0+dy, zc=z0+dz;
        bool valid = (xc>=0)&(xc<64)&(yc>=0)&(yc<64)&(zc>=0)&(zc<64);
        float wk = (dx?fxr:1.f-fxr)*(dy?fyr:1.f-fyr)*(dz?fzr:1.f-fzr);
        cw[k] = valid ? wk : 0.0f;
        int xcc = min(max(xc,0),63), ycc=min(max(yc,0),63), zcc=min(max(zc,0),63);
        offs[k] = (zcc*64 + ycc)*64 + xcc;
      }
      #pragma unroll
      for (int k=0;k<8;k++) sigma += cw[k]*dp[offs[k]];

      float wgt = sigma * Trun;
      if (wgt > 1e-7f){
        #pragma unroll
        for (int k=0;k<8;k++){
          const uint4* p = (const uint4*)(vb + (size_t)offs[k]*16);
          uint4 q0 = p[0];
          uint4 q1 = p[1];
          float wk = cw[k]*wgt;
          acc2(q0.x, wk, vch[0],  vch[1]);
          acc2(q0.y, wk, vch[2],  vch[3]);
          acc2(q0.z, wk, vch[4],  vch[5]);
          acc2(q0.w, wk, vch[6],  vch[7]);
          acc2(q1.x, wk, vch[8],  vch[9]);
          acc2(q1.y, wk, vch[10], vch[11]);
          acc2(q1.z, wk, vch[12], vch[13]);
          acc2(q1.w, wk, vch[14], vch[15]);
        }
      }
    }
    Trun *= (1.0f + 1e-10f - sigma);
    Pop  *= (1.0f - sigma);
    if (__ballot(Trun > 1e-7f) == 0ULL) break;
  }

  g_sil[b*4096 + h*64 + w] = 1.0f - Pop;
  uint pk[8];
  #pragma unroll
  for (int c2=0;c2<8;c2++)
    pk[c2] = (uint)bdn(vch[2*c2]) | ((uint)bdn(vch[2*c2+1])<<16);
  uint* dst = (uint*)(g_imgT + ((size_t)(b*4096) + h*64 + w)*16);
  uint4 lo; lo.x=pk[0]; lo.y=pk[1]; lo.z=pk[2]; lo.w=pk[3];
  uint4 hi; hi.x=pk[4]; hi.y=pk[5]; hi.z=pk[6]; hi.w=pk[7];
  *(uint4*)dst = lo;
  *(uint4*)(dst+4) = hi;
}

// ---------------------------------------------------------------------------
// K2: ConvTranspose2d via MFMA. grid 512 = 8b x 64 input-rows.
// wave = parity class (dr,dc); C[o16][px16], K = 9taps x 16ic (5 steps).
// ---------------------------------------------------------------------------
__global__ __launch_bounds__(256) void k_convt(const float* __restrict__ bt)
{
  __shared__ __align__(16) short tile[3*66*16];
  __shared__ float ssum[4][16], ssq[4][16];

  int blk = blockIdx.x;
  int r = blk & 63, b = blk >> 6;
  int tid = threadIdx.x;

  for (int idx = tid; idx < 396; idx += 256){
    int row3 = idx / 132; int rem = idx - row3*132;
    int c2 = rem >> 1, half = rem & 1;
    int gr = r - 1 + row3, gc = c2 - 1;
    uint4 val = make_uint4(0,0,0,0);
    if (gr>=0 && gr<64 && gc>=0 && gc<64)
      val = *(const uint4*)(g_imgT + ((size_t)(b*4096) + gr*64 + gc)*16 + half*8);
    *(uint4*)(tile + (row3*66 + c2)*16 + half*8) = val;
  }
  __syncthreads();

  int wv = tid >> 6, lane = tid & 63;
  int dr = wv >> 1, dc = wv & 1;
  int quad = lane >> 4, col = lane & 15;
  int ic0 = (quad & 1) * 8;

  f32x4 acc[4];
  #pragma unroll
  for (int n=0;n<4;n++) acc[n] = (f32x4){0.f,0.f,0.f,0.f};

  #pragma unroll
  for (int s5=0; s5<5; ++s5){
    frag a = *(const frag*)(g_wAt + ((wv*5 + s5)*64 + lane)*8);
    int tau = 2*s5 + (quad >> 1);
    if (tau > 8) tau = 0;
    int ss = tau/3, tt = tau%3;
    #pragma unroll
    for (int n=0;n<4;n++){
      int c2 = n*16 + col + tt;
      frag bf = *(const frag*)(tile + (ss*66 + c2)*16 + ic0);
      acc[n] = mf(a, bf, acc[n]);
    }
  }

  float4 bo = *(const float4*)(bt + quad*4);
  float bor[4] = {bo.x, bo.y, bo.z, bo.w};
  float sv[4] = {0,0,0,0}, qv[4] = {0,0,0,0};
  int orow = 2*r + dr;
  #pragma unroll
  for (int n=0;n<4;n++){
    int ocol = 2*(n*16 + col) + dc;
    bf16* dst = g_t1 + ((size_t)(b*128 + orow)*128 + ocol)*16 + quad*4;
    #pragma unroll
    for (int reg=0;reg<4;reg++){
      float vvv = acc[n][reg] + bor[reg];
      dst[reg] = __float2bfloat16(vvv);
      sv[reg] += vvv; qv[reg] += vvv*vvv;
    }
  }
  #pragma unroll
  for (int m=1; m<16; m<<=1){
    #pragma unroll
    for (int reg=0;reg<4;reg++){
      sv[reg] += __shfl_xor(sv[reg], m, 64);
      qv[reg] += __shfl_xor(qv[reg], m, 64);
    }
  }
  if ((lane & 15) == 0){
    #pragma unroll
    for (int reg=0;reg<4;reg++){
      ssum[wv][quad*4+reg] = sv[reg];
      ssq [wv][quad*4+reg] = qv[reg];
    }
  }
  __syncthreads();
  if (tid < 16){
    g_part[blk*32 + tid]      = ssum[0][tid]+ssum[1][tid]+ssum[2][tid]+ssum[3][tid];
    g_part[blk*32 + 16 + tid] = ssq[0][tid]+ssq[1][tid]+ssq[2][tid]+ssq[3][tid];
  }
}

// ---------------------------------------------------------------------------
__global__ __launch_bounds__(256) void k_fin1(const float* __restrict__ g,
                                              const float* __restrict__ be)
{
  __shared__ float rs[256], rq[256];
  int tid = threadIdx.x; int c = tid>>4, seg = tid&15;
  float s=0.f, q=0.f;
  for (int k=0;k<32;k++){
    int blk = seg*32+k;
    s += g_part[blk*32 + c];
    q += g_part[blk*32 + 16 + c];
  }
  rs[tid]=s; rq[tid]=q; __syncthreads();
  for (int sft=8; sft>0; sft>>=1){
    if (seg<sft){ rs[tid]+=rs[tid+sft]; rq[tid]+=rq[tid+sft]; }
    __syncthreads();
  }
  if (seg==0){
    float m = rs[tid]*(1.0f/131072.f);
    float v = rq[tid]*(1.0f/131072.f) - m*m;
    float a = g[c]*rsqrtf(v+1e-5f);
    g_stats[32+c] = a; g_stats[48+c] = be[c]-m*a;
  }
}

__global__ __launch_bounds__(256) void k_fin2(const float* __restrict__ g,
                                              const float* __restrict__ be)
{
  __shared__ float rs[256], rq[256];
  int tid = threadIdx.x; int seg = tid & 31, c = tid >> 5;
  float s=0.f, q=0.f;
  for (int k=0;k<8;k++){
    int blk = seg*8+k;
    s += g_part2[blk*16 + c];
    q += g_part2[blk*16 + 8 + c];
  }
  rs[tid]=s; rq[tid]=q; __syncthreads();
  for (int sft=16; sft>0; sft>>=1){
    if (seg<sft){ rs[tid]+=rs[tid+sft]; rq[tid]+=rq[tid+sft]; }
    __syncthreads();
  }
  if (seg==0){
    float m = rs[tid]*(1.0f/131072.f);
    float v = rq[tid]*(1.0f/131072.f) - m*m;
    float a = g[c]*rsqrtf(v+1e-5f);
    g_stats[80+c] = a; g_stats[88+c] = be[c]-m*a;
  }
}

// ---------------------------------------------------------------------------
// K3: conv1 5x5 (16->8) via MFMA, BN1+leaky fused into staging.
// ---------------------------------------------------------------------------
__global__ __launch_bounds__(256) void k_conv1(const float* __restrict__ b1)
{
  __shared__ __align__(16) short tile[8*132*16];
  __shared__ float ssum[4][8], ssq[4][8];

  int blk = blockIdx.x;
  int rt = blk & 31, b = blk >> 5;
  int tid = threadIdx.x;

  float pa[16], pb[16];
  #pragma unroll
  for (int c=0;c<16;c++){ pa[c] = g_stats[32+c]; pb[c] = g_stats[48+c]; }

  for (int it=0; it<5; ++it){
    int idx = it*256 + tid;
    if (idx < 1056){
      int r8 = idx / 132; int c2 = idx - r8*132;
      int gr = rt*4 - 2 + r8, gc = c2 - 2;
      uint4 v0 = make_uint4(0,0,0,0), v1 = make_uint4(0,0,0,0);
      if (gr>=0 && gr<128 && gc>=0 && gc<128){
        const bf16* src = g_t1 + ((size_t)(b*128 + gr)*128 + gc)*16;
        v0 = *(const uint4*)(src);
        v1 = *(const uint4*)(src + 8);
        v0.x = aff2(v0.x, pa[0],pb[0],pa[1],pb[1]);
        v0.y = aff2(v0.y, pa[2],pb[2],pa[3],pb[3]);
        v0.z = aff2(v0.z, pa[4],pb[4],pa[5],pb[5]);
        v0.w = aff2(v0.w, pa[6],pb[6],pa[7],pb[7]);
        v1.x = aff2(v1.x, pa[8],pb[8],pa[9],pb[9]);
        v1.y = aff2(v1.y, pa[10],pb[10],pa[11],pb[11]);
        v1.z = aff2(v1.z, pa[12],pb[12],pa[13],pb[13]);
        v1.w = aff2(v1.w, pa[14],pb[14],pa[15],pb[15]);
      }
      *(uint4*)(tile + (r8*132 + c2)*16)     = v0;
      *(uint4*)(tile + (r8*132 + c2)*16 + 8) = v1;
    }
  }
  __syncthreads();

  int wv = tid >> 6, lane = tid & 63;
  int quad = lane >> 4, col = lane & 15;
  int ic0 = (quad & 1) * 8;

  f32x4 acc[8];
  #pragma unroll
  for (int n=0;n<8;n++) acc[n] = (f32x4){0.f,0.f,0.f,0.f};

  for (int s13=0; s13<13; ++s13){
    frag a = *(const frag*)(g_wA1 + (s13*64 + lane)*8);
    int tau = 2*s13 + (quad >> 1);
    if (tau > 24) tau = 0;
    int dh = tau/5, dw = tau%5;
    int rowt = wv + dh;
    #pragma unroll
    for (int n=0;n<8;n++){
      int c2 = n*16 + col + dw;
      frag bf = *(const frag*)(tile + (rowt*132 + c2)*16 + ic0);
      acc[n] = mf(a, bf, acc[n]);
    }
  }

  int row = rt*4 + wv;
  float sv[4] = {0,0,0,0}, qv[4] = {0,0,0,0};
  if (quad < 2){
    float4 bo = *(const float4*)(b1 + quad*4);
    float bor[4] = {bo.x, bo.y, bo.z, bo.w};
    #pragma unroll
    for (int n=0;n<8;n++){
      int px = n*16 + col;
      bf16* dst = g_a2r + ((size_t)(b*128 + row)*128 + px)*8 + quad*4;
      #pragma unroll
      for (int reg=0;reg<4;reg++){
        float vvv = acc[n][reg] + bor[reg];
        dst[reg] = __float2bfloat16(vvv);
        sv[reg] += vvv; qv[reg] += vvv*vvv;
      }
    }
  }
  #pragma unroll
  for (int m=1; m<16; m<<=1){
    #pragma unroll
    for (int reg=0;reg<4;reg++){
      sv[reg] += __shfl_xor(sv[reg], m, 64);
      qv[reg] += __shfl_xor(qv[reg], m, 64);
    }
  }
  if ((lane & 15) == 0 && quad < 2){
    #pragma unroll
    for (int reg=0;reg<4;reg++){
      ssum[wv][quad*4+reg] = sv[reg];
      ssq [wv][quad*4+reg] = qv[reg];
    }
  }
  __syncthreads();
  if (tid < 8){
    g_part2[blk*16 + tid]     = ssum[0][tid]+ssum[1][tid]+ssum[2][tid]+ssum[3][tid];
    g_part2[blk*16 + 8 + tid] = ssq[0][tid]+ssq[1][tid]+ssq[2][tid]+ssq[3][tid];
  }
}

// ---------------------------------------------------------------------------
// K4: conv2 5x5 (8->3) via MFMA, BN2+leaky fused into staging. ReLU -> d_out.
// ---------------------------------------------------------------------------
__global__ __launch_bounds__(256) void k_conv2(float* __restrict__ outp,
                                               const float* __restrict__ b2)
{
  __shared__ __align__(16) short tile[8*132*8];

  int blk = blockIdx.x;
  int rt = blk & 31, b = blk >> 5;
  int tid = threadIdx.x;

  float pa[8], pb[8];
  #pragma unroll
  for (int c=0;c<8;c++){ pa[c] = g_stats[80+c]; pb[c] = g_stats[88+c]; }

  for (int it=0; it<5; ++it){
    int idx = it*256 + tid;
    if (idx < 1056){
      int r8 = idx / 132; int c2 = idx - r8*132;
      int gr = rt*4 - 2 + r8, gc = c2 - 2;
      uint4 v0 = make_uint4(0,0,0,0);
      if (gr>=0 && gr<128 && gc>=0 && gc<128){
        v0 = *(const uint4*)(g_a2r + ((size_t)(b*128 + gr)*128 + gc)*8);
        v0.x = aff2(v0.x, pa[0],pb[0],pa[1],pb[1]);
        v0.y = aff2(v0.y, pa[2],pb[2],pa[3],pb[3]);
        v0.z = aff2(v0.z, pa[4],pb[4],pa[5],pb[5]);
        v0.w = aff2(v0.w, pa[6],pb[6],pa[7],pb[7]);
      }
      *(uint4*)(tile + (r8*132 + c2)*8) = v0;
    }
  }
  __syncthreads();

  int wv = tid >> 6, lane = tid & 63;
  int quad = lane >> 4, col = lane & 15;

  f32x4 acc[8];
  #pragma unroll
  for (int n=0;n<8;n++) acc[n] = (f32x4){0.f,0.f,0.f,0.f};

  for (int s7=0; s7<7; ++s7){
    frag a = *(const frag*)(g_wA2 + (s7*64 + lane)*8);
    int tau = 4*s7 + quad;
    if (tau > 24) tau = 0;
    int dh = tau/5, dw = tau%5;
    int rowt = wv + dh;
    #pragma unroll
    for (int n=0;n<8;n++){
      int c2 = n*16 + col + dw;
      frag bf = *(const frag*)(tile + (rowt*132 + c2)*8);
      acc[n] = mf(a, bf, acc[n]);
    }
  }

  if (quad == 0){
    int row = rt*4 + wv;
    float b2v[3] = {b2[0], b2[1], b2[2]};
    #pragma unroll
    for (int n=0;n<8;n++){
      int px = n*16 + col;
      #pragma unroll
      for (int reg=0;reg<3;reg++){
        float vvv = fmaxf(acc[n][reg] + b2v[reg], 0.f);
        outp[(size_t)(b*3 + reg)*16384 + row*128 + px] = vvv;
      }
    }
  }
}

// ---------------------------------------------------------------------------
__global__ __launch_bounds__(256) void k_silup(float* __restrict__ outp)
{
  int idx = blockIdx.x*256 + threadIdx.x;
  if (idx >= 8*16384) return;
  int b = idx >> 14;
  int y = (idx >> 7) & 127;
  int x = idx & 127;
  float sy = y*0.5f - 0.25f, sx = x*0.5f - 0.25f;
  float yfl = floorf(sy), xfl = floorf(sx);
  float fy = sy - yfl, fx = sx - xfl;
  int y0 = min(max((int)yfl,0),63), y1 = min(max((int)yfl+1,0),63);
  int x0 = min(max((int)xfl,0),63), x1 = min(max((int)xfl+1,0),63);
  const float* s = g_sil + b*4096;
  float vv = (1.f-fy)*((1.f-fx)*s[y0*64+x0] + fx*s[y0*64+x1])
           +      fy *((1.f-fx)*s[y1*64+x0] + fx*s[y1*64+x1]);
  outp[idx] = vv;
}

// ---------------------------------------------------------------------------
extern "C" void kernel_launch(void* const* d_in, const int* in_sizes, int n_in,
                              void* d_out, int out_size, void* d_ws, size_t ws_size,
                              hipStream_t stream)
{
  const float* R    = (const float*)d_in[0];
  const float* T    = (const float*)d_in[1];
  const float* K    = (const float*)d_in[2];
  const float* feat = (const float*)d_in[3];
  const float* dens = (const float*)d_in[4];
  const float* wt   = (const float*)d_in[5];
  const float* bt   = (const float*)d_in[6];
  const float* g1   = (const float*)d_in[7];
  const float* be1  = (const float*)d_in[8];
  const float* w1   = (const float*)d_in[9];
  const float* b1   = (const float*)d_in[10];
  const float* g2   = (const float*)d_in[11];
  const float* be2  = (const float*)d_in[12];
  const float* w2   = (const float*)d_in[13];
  const float* b2   = (const float*)d_in[14];

  k_wprep    <<<1, 256, 0, stream>>>(wt, w1, w2);
  k_transpose<<<8192, 256, 0, stream>>>(feat);
  k_render   <<<512, 64, 0, stream>>>(R, T, K, dens);
  k_convt    <<<512, 256, 0, stream>>>(bt);
  k_fin1     <<<1, 256, 0, stream>>>(g1, be1);
  k_conv1    <<<256, 256, 0, stream>>>(b1);
  k_fin2     <<<1, 256, 0, stream>>>(g2, be2);
  k_conv2    <<<256, 256, 0, stream>>>((float*)d_out, b2);
  k_silup    <<<512, 256, 0, stream>>>((float*)d_out + 393216);
}